// Round 4
// baseline (7110.814 us; speedup 1.0000x reference)
//
#include <hip/hip_runtime.h>
#include <hip/hip_cooperative_groups.h>
#include <math.h>

namespace cg = cooperative_groups;

#define Bq 32
#define Sq 512
#define Tq 32
#define EMBq 256
#define HIDq 512
#define VOCABq 50000
#define OOVq 100
#define VEXTq (VOCABq + OOVq)
#define HALF_N 25088   /* padded half of vocab for WT buffer (196*128) */

typedef unsigned short u16;
typedef __attribute__((ext_vector_type(8))) short bf16x8;
typedef __attribute__((ext_vector_type(4))) float f32x4;

__device__ __forceinline__ float sigmoidf_(float x){ return 1.0f/(1.0f+__expf(-x)); }
__device__ __forceinline__ float tanhf_(float x){ return 1.0f - 2.0f/(__expf(2.0f*x)+1.0f); }

__device__ __forceinline__ u16 f2bf(float x){
  union{float f; unsigned u;} v; v.f=x;
  unsigned r = v.u + 0x7FFFu + ((v.u>>16)&1u);
  return (u16)(r>>16);
}

__device__ __forceinline__ float blockSum512(float v, float* red){
  #pragma unroll
  for (int off=32; off>0; off>>=1) v += __shfl_down(v, off);
  int lane = threadIdx.x & 63, wid = threadIdx.x >> 6;
  __syncthreads();
  if (lane==0) red[wid]=v;
  __syncthreads();
  float t=0.f;
  #pragma unroll
  for (int w=0;w<8;++w) t+=red[w];
  return t;
}

// ---- enc_feat = encoder_states @ W_enc + b_enc ----
__global__ __launch_bounds__(512) void k_enc(const float* __restrict__ es,
    const float* __restrict__ W_enc, const float* __restrict__ b_enc,
    float* __restrict__ ef){
  __shared__ float A[16][256];
  const int tid = threadIdx.x;
  const int r0  = blockIdx.x * 16;
  float acc[16];
  #pragma unroll
  for (int r=0;r<16;++r) acc[r]=0.f;
  for (int kc=0;kc<2;++kc){
    __syncthreads();
    for (int i=tid;i<16*256;i+=512){
      int rr=i>>8, kk=i&255;
      A[rr][kk]=es[(size_t)(r0+rr)*HIDq + kc*256 + kk];
    }
    __syncthreads();
    for (int k=0;k<256;++k){
      float w=W_enc[(size_t)(kc*256+k)*HIDq + tid];
      #pragma unroll
      for (int r=0;r<16;++r) acc[r]+=A[r][k]*w;
    }
  }
  float bb=b_enc[tid];
  #pragma unroll
  for (int r=0;r<16;++r) ef[(size_t)(r0+r)*HIDq+tid]=acc[r]+bb;
}

// ---- embx[t*32+b,:] = emb(dec_ids[b,t]) @ W_x[0:256,:]; embxp = embx . Wp4 ----
__global__ __launch_bounds__(512) void k_embx(const int* __restrict__ dec_ids,
  const float* __restrict__ emb, const float* __restrict__ W_x,
  const float* __restrict__ Wpgen, float* __restrict__ embx, float* __restrict__ embxp){
  __shared__ float A[16][257];
  __shared__ int ids[16];
  __shared__ float red[8];
  const int tid = threadIdx.x, r0 = blockIdx.x*16;
  if (tid<16){
    int row = r0+tid, tt = row>>5, bb = row&31;
    ids[tid] = dec_ids[bb*Tq + tt];
  }
  __syncthreads();
  for (int idx=tid; idx<16*256; idx+=512){
    int rr = idx>>8, kk = idx&255;
    A[rr][kk] = emb[(size_t)ids[rr]*EMBq + kk];
  }
  __syncthreads();
  float acc[16];
  #pragma unroll
  for (int r=0;r<16;++r) acc[r]=0.f;
  for (int k=0;k<256;++k){
    float w = W_x[(size_t)k*HIDq + tid];
    #pragma unroll
    for (int r=0;r<16;++r) acc[r] += A[r][k]*w;
  }
  float wp4 = Wpgen[1536+tid];
  for (int r=0;r<16;++r){
    embx[(size_t)(r0+r)*HIDq + tid] = acc[r];
    float s = blockSum512(acc[r]*wp4, red);
    if (tid==0) embxp[r0+r] = s;
  }
}

// ---- embz = embx @ Wk + b_lstm   [1024,512]x[512,2048] ----
__global__ __launch_bounds__(512) void k_embz(const float* __restrict__ embx,
  const float* __restrict__ Wk, const float* __restrict__ b_lstm, float* __restrict__ embz){
  __shared__ float A[16][513];
  const int tid = threadIdx.x;
  const int r0 = blockIdx.x*16;
  const int n  = blockIdx.y*512 + tid;
  for (int idx=tid; idx<16*512; idx+=512){
    int rr=idx>>9, kk=idx&511;
    A[rr][kk] = embx[(size_t)(r0+rr)*HIDq + kk];
  }
  __syncthreads();
  float acc[16];
  #pragma unroll
  for (int r=0;r<16;++r) acc[r]=0.f;
  for (int k=0;k<512;++k){
    float w = Wk[(size_t)k*2048 + n];
    #pragma unroll
    for (int r=0;r<16;++r) acc[r] += A[r][k]*w;
  }
  float bl = b_lstm[n];
  #pragma unroll
  for (int r=0;r<16;++r) embz[(size_t)(r0+r)*2048 + n] = acc[r]+bl;
}

// ---- WXKT[n][j] = sum_i Wk[i][n] * W_x[256+j][i] ----
__global__ __launch_bounds__(512) void k_wxk(const float* __restrict__ Wk,
    const float* __restrict__ W_x, float* __restrict__ WXKT_){
  __shared__ float KT[32][64];
  __shared__ float X2[32][33];
  const int tid = threadIdx.x;
  const int n0 = blockIdx.x * 64;
  const int j0 = blockIdx.y * 32;
  const int jj = tid & 31;
  const int ng = tid >> 5;   // 0..15
  float acc[4] = {0,0,0,0};
  for (int i0=0;i0<512;i0+=32){
    __syncthreads();
    for (int idx=tid; idx<32*64; idx+=512){
      int ii = idx>>6, nn = idx&63;
      KT[ii][nn] = Wk[(size_t)(i0+ii)*2048 + n0+nn];
    }
    for (int idx=tid; idx<32*32; idx+=512){
      int j2 = idx>>5, i2 = idx&31;
      X2[j2][i2] = W_x[(size_t)(256+j0+j2)*HIDq + i0+i2];
    }
    __syncthreads();
    for (int ii=0;ii<32;++ii){
      float xv = X2[jj][ii];
      #pragma unroll
      for (int q=0;q<4;++q) acc[q] += KT[ii][ng*4+q]*xv;
    }
  }
  #pragma unroll
  for (int q=0;q<4;++q) WXKT_[(size_t)(n0+ng*4+q)*512 + j0+jj] = acc[q];
}

// ---- generic 32x32 tiled transpose: out[n][k] = in[k][n], in is [K][N] ----
__global__ __launch_bounds__(512) void k_trans(const float* __restrict__ in,
    float* __restrict__ out, int K, int N){
  __shared__ float T[32][33];
  const int n0 = blockIdx.x*32, k0 = blockIdx.y*32;
  const int tid = threadIdx.x;
  for (int idx=tid; idx<1024; idx+=512){
    int kk = idx>>5, nn = idx&31;
    T[kk][nn] = in[(size_t)(k0+kk)*N + n0+nn];
  }
  __syncthreads();
  for (int idx=tid; idx<1024; idx+=512){
    int nn = idx>>5, kk = idx&31;
    out[(size_t)(n0+nn)*K + k0+kk] = T[kk][nn];
  }
}

// ---- Wxp[j] = sum_i W_x[256+j][i]*W_pgen[1536+i] ----
__global__ __launch_bounds__(512) void k_wp(const float* __restrict__ W_x,
  const float* __restrict__ Wpgen, float* __restrict__ Wxp){
  int j = threadIdx.x;
  const float* row = W_x + (size_t)(256+j)*HIDq;
  float s=0.f;
  for (int i=0;i<512;++i) s += row[i]*Wpgen[1536+i];
  Wxp[j] = s;
}

// ==== persistent cooperative recurrence ====
// grid 256 x 512. Phase A: gates/LSTM, col-partitioned (2 cols/block).
// Phase B: blocks 0..31, one per batch: df, e, softmax, cov(LDS-resident), ctx, pgen.
__global__ __launch_bounds__(512,1) void k_rec2(
  const float* __restrict__ EF, const float* __restrict__ mask,
  const float* __restrict__ init_h, const float* __restrict__ init_c,
  const float* __restrict__ WXKT_, const float* __restrict__ WrT_,
  const float* __restrict__ embz, const float* __restrict__ embxp,
  const float* __restrict__ W_attn, const float* __restrict__ vvec,
  const float* __restrict__ wcov, const float* __restrict__ bcov,
  const float* __restrict__ Wpgen, const float* __restrict__ Wxp,
  float* __restrict__ Hbuf, float* __restrict__ Cbuf, float* __restrict__ Ctx,
  float* __restrict__ hc_ws, float* __restrict__ attn_ws, float* __restrict__ pgen_ws)
{
  cg::grid_group grid = cg::this_grid();
  __shared__ union {
    struct { float Sctx[32][516]; float Sh[32][516]; } a;                 // 132KB
    struct { float hb[512], cb[512], cpb[512], dfl[512], el[512], at[512],
             red[8], redm[8]; } b;                                        // 12KB
  } u;
  __shared__ float covb[512];
  __shared__ float gbuf[4][2][32];

  const int tid = threadIdx.x, bid = blockIdx.x;
  // phase A decomposition
  const int bA = tid & 31, slot = tid >> 5;
  const int colA = bid*2 + (slot>>3);
  const int gA = (slot>>1)&3;
  const int halfA = slot&1;
  const float* WArow = (halfA ? WrT_ : WXKT_) + (size_t)(gA*512 + colA)*512;
  // phase B lane geometry + step-invariant vectors
  const int wv = tid>>6, lane = tid&63, j0 = lane*8;
  float vv[8], wc[8], bc[8];
  if (bid < 32){
    *(float4*)&vv[0] = *(const float4*)&vvec[j0]; *(float4*)&vv[4] = *(const float4*)&vvec[j0+4];
    *(float4*)&wc[0] = *(const float4*)&wcov[j0]; *(float4*)&wc[4] = *(const float4*)&wcov[j0+4];
    *(float4*)&bc[0] = *(const float4*)&bcov[j0]; *(float4*)&bc[4] = *(const float4*)&bcov[j0+4];
  }

  for (int t=0; t<Tq; ++t){
    // ================= phase A: gates + LSTM =================
    {
      const float* hsrc = (t==0) ? init_h : Hbuf;
      for (int idx=tid; idx<32*128; idx+=512){
        int b2 = idx>>7, k4 = (idx&127)*4;
        *(float4*)&u.a.Sh[b2][k4] = *(const float4*)&hsrc[b2*512+k4];
        if (t>0) *(float4*)&u.a.Sctx[b2][k4] = *(const float4*)&Ctx[b2*512+k4];
      }
      __syncthreads();
      float acc = (halfA==0) ? embz[((size_t)t*Bq+bA)*2048 + gA*512 + colA] : 0.f;
      if (!(t==0 && halfA==0)){
        const float* Srow = halfA ? u.a.Sh[bA] : u.a.Sctx[bA];
        float a0=0.f,a1=0.f,a2=0.f,a3=0.f;
        for (int k=0;k<512;k+=16){
          float4 s0 = *(const float4*)&Srow[k],    w0 = *(const float4*)&WArow[k];
          float4 s1 = *(const float4*)&Srow[k+4],  w1 = *(const float4*)&WArow[k+4];
          float4 s2 = *(const float4*)&Srow[k+8],  w2 = *(const float4*)&WArow[k+8];
          float4 s3 = *(const float4*)&Srow[k+12], w3 = *(const float4*)&WArow[k+12];
          a0 += s0.x*w0.x + s0.y*w0.y + s0.z*w0.z + s0.w*w0.w;
          a1 += s1.x*w1.x + s1.y*w1.y + s1.z*w1.z + s1.w*w1.w;
          a2 += s2.x*w2.x + s2.y*w2.y + s2.z*w2.z + s2.w*w2.w;
          a3 += s3.x*w3.x + s3.y*w3.y + s3.z*w3.z + s3.w*w3.w;
        }
        acc += (a0+a1)+(a2+a3);
      }
      acc += __shfl_xor(acc, 32);          // combine ctx-half and h-half
      if ((tid&63) < 32) gbuf[gA][slot>>3][bA] = acc;
      __syncthreads();
      if (tid < 64){
        int b2 = tid&31, ci = tid>>5, col = bid*2+ci;
        float zi = gbuf[0][ci][b2], zf = gbuf[1][ci][b2];
        float zg = gbuf[2][ci][b2], zo = gbuf[3][ci][b2];
        float co = (t==0) ? init_c[b2*512+col] : Cbuf[b2*512+col];
        float cn = sigmoidf_(zf)*co + sigmoidf_(zi)*tanhf_(zg);
        float hn = sigmoidf_(zo)*tanhf_(cn);
        Cbuf[b2*512+col] = cn;
        Hbuf[b2*512+col] = hn;
        hc_ws[((size_t)t*Bq+b2)*1024 + col] = hn;
      }
    }
    grid.sync();
    // ================= phase B: attention (blocks 0..31) =================
    if (bid < 32){
      const int b = bid;
      u.b.hb[tid]  = Hbuf[b*512+tid];
      u.b.cb[tid]  = Cbuf[b*512+tid];
      u.b.cpb[tid] = (t==0) ? 0.f : Ctx[b*512+tid];
      __syncthreads();
      // df[i] = [h;c] . W_attn[:,i]
      {
        float d0=0.f, d1=0.f;
        const float* wa  = W_attn + tid;
        const float* wa2 = W_attn + (size_t)512*512 + tid;
        #pragma unroll 4
        for (int k=0;k<512;++k){
          d0 += u.b.hb[k]*wa[0];  wa  += 512;
          d1 += u.b.cb[k]*wa2[0]; wa2 += 512;
        }
        u.b.dfl[tid] = d0+d1;
      }
      __syncthreads();
      // e[s]: wave wv handles s in [wv*64, wv*64+64), lanes partition j
      float dd[8];
      *(float4*)&dd[0] = *(const float4*)&u.b.dfl[j0];
      *(float4*)&dd[4] = *(const float4*)&u.b.dfl[j0+4];
      const float* efbase = EF + (size_t)b*512*512;
      for (int r=0;r<64;++r){
        const int s = wv*64 + r;
        const float* efr = efbase + (size_t)s*512 + j0;
        float ef[8];
        *(float4*)&ef[0] = *(const float4*)efr;
        *(float4*)&ef[4] = *(const float4*)(efr+4);
        float a8 = 0.f;
        if (t>0){
          const float cvs = covb[s];
          #pragma unroll
          for (int q=0;q<8;++q) a8 += vv[q]*tanhf_(ef[q]+dd[q]+cvs*wc[q]+bc[q]);
        } else {
          #pragma unroll
          for (int q=0;q<8;++q) a8 += vv[q]*tanhf_(ef[q]+dd[q]);
        }
        #pragma unroll
        for (int off=32; off>0; off>>=1) a8 += __shfl_down(a8, off);
        if (lane==0) u.b.el[s] = a8;
      }
      __syncthreads();
      // masked softmax over 512
      float ee = u.b.el[tid];
      float m = ee;
      #pragma unroll
      for (int off=32; off>0; off>>=1) m = fmaxf(m, __shfl_xor(m, off));
      if (lane==0) u.b.redm[wv] = m;
      __syncthreads();
      float M = u.b.redm[0];
      #pragma unroll
      for (int w=1;w<8;++w) M = fmaxf(M, u.b.redm[w]);
      float w_ = mask[b*512+tid]*__expf(ee-M);
      float ss = w_;
      #pragma unroll
      for (int off=32; off>0; off>>=1) ss += __shfl_xor(ss, off);
      if (lane==0) u.b.red[wv] = ss;
      __syncthreads();
      float S = 0.f;
      #pragma unroll
      for (int w=0;w<8;++w) S += u.b.red[w];
      float a_ = w_/S;
      u.b.at[tid] = a_;
      attn_ws[((size_t)t*Bq+b)*Sq + tid] = a_;
      covb[tid] = (t==0) ? a_ : covb[tid]+a_;
      __syncthreads();
      // ctx[j] = sum_s attn[s]*EF[b][s][j]
      float cx = 0.f;
      {
        const float* efc = efbase + tid;
        #pragma unroll 4
        for (int s=0;s<512;++s){ cx += u.b.at[s]*efc[0]; efc += 512; }
      }
      const float cold = u.b.cpb[tid];
      Ctx[b*512+tid] = cx;
      hc_ws[((size_t)t*Bq+b)*1024 + 512 + tid] = cx;
      // p_gen (with correct ctx_prev term through x)
      float val = cx*Wpgen[tid] + u.b.hb[tid]*Wpgen[512+tid]
                + u.b.cb[tid]*Wpgen[1024+tid] + cold*Wxp[tid];
      #pragma unroll
      for (int off=32; off>0; off>>=1) val += __shfl_down(val, off);
      if (lane==0) u.b.red[wv] = val;
      __syncthreads();
      if (tid==0){
        float tot = 0.f;
        #pragma unroll
        for (int w=0;w<8;++w) tot += u.b.red[w];
        pgen_ws[t*Bq+b] = sigmoidf_(tot + embxp[t*Bq+b]);
      }
    }
    grid.sync();
  }
}

// ---- OUTm = [h,ctx] @ W_out  -> bf16 ----
__global__ __launch_bounds__(512) void k_mid(const float* __restrict__ hc,
    const float* __restrict__ W_out, u16* __restrict__ outm_bf){
  __shared__ float A[16][256];
  const int tid=threadIdx.x;
  const int r0=blockIdx.x*16;
  float acc[16];
  #pragma unroll
  for (int r=0;r<16;++r) acc[r]=0.f;
  for (int kc=0;kc<4;++kc){
    __syncthreads();
    for (int i=tid;i<16*256;i+=512){
      int rr=i>>8, kk=i&255;
      A[rr][kk]=hc[(size_t)(r0+rr)*1024 + kc*256+kk];
    }
    __syncthreads();
    for (int k=0;k<256;++k){
      float w=W_out[(size_t)(kc*256+k)*HIDq + tid];
      #pragma unroll
      for (int r=0;r<16;++r) acc[r]+=A[r][k]*w;
    }
  }
  #pragma unroll
  for (int r=0;r<16;++r) outm_bf[(size_t)(r0+r)*HIDq+tid]=f2bf(acc[r]);
}

// ---- W_proj f32 [512][50000] -> WT bf16 [HALF_N][512] (transposed half) ----
__global__ __launch_bounds__(256) void k_wcvt(const float* __restrict__ Wp,
    u16* __restrict__ WT, int n_base){
  __shared__ float T[32][33];
  const int n0 = blockIdx.x*32, k0 = blockIdx.y*32;
  const int tid = threadIdx.x;
  #pragma unroll
  for (int it=0; it<4; ++it){
    int id = tid + it*256;
    int kk = id>>5, nn = id&31;
    int gn = n_base + n0 + nn;
    T[kk][nn] = (gn < VOCABq) ? Wp[(size_t)(k0+kk)*VOCABq + gn] : 0.f;
  }
  __syncthreads();
  #pragma unroll
  for (int it=0; it<4; ++it){
    int id = tid + it*256;
    int nn = id>>5, kk = id&31;
    WT[(size_t)(n0+nn)*512 + k0+kk] = f2bf(T[kk][nn]);
  }
}

// ---- logits = Abf[1024,512] @ WT^T + b_proj -> d_out (f32), MFMA bf16 ----
__global__ __launch_bounds__(256) void k_projm(const u16* __restrict__ Abf,
    const u16* __restrict__ WT, const float* __restrict__ b_proj,
    float* __restrict__ out, int n_base){
  __shared__ u16 As[128*40];
  __shared__ u16 Bs[128*40];
  const int tid = threadIdx.x;
  const int m0 = blockIdx.x * 128;
  const int n0 = blockIdx.y * 128;
  const int wid = tid>>6, lane = tid&63;
  const int wm = (wid>>1)*64, wn = (wid&1)*64;
  const int l15 = lane&15, l4 = lane>>4;
  f32x4 acc[4][4];
  #pragma unroll
  for (int mi=0;mi<4;++mi)
    #pragma unroll
    for (int ni=0;ni<4;++ni) acc[mi][ni] = (f32x4){0.f,0.f,0.f,0.f};

  for (int kt=0; kt<16; ++kt){
    const int k0 = kt*32;
    __syncthreads();
    #pragma unroll
    for (int it=0; it<2; ++it){
      int id = tid + it*256;
      int row = id>>2, c4 = id&3;
      uint4 va = *(const uint4*)(Abf + (size_t)(m0+row)*512 + k0 + c4*8);
      *(uint4*)(&As[row*40 + c4*8]) = va;
      uint4 vb = *(const uint4*)(WT + (size_t)(n0+row)*512 + k0 + c4*8);
      *(uint4*)(&Bs[row*40 + c4*8]) = vb;
    }
    __syncthreads();
    bf16x8 a[4], b[4];
    #pragma unroll
    for (int mi=0;mi<4;++mi)
      a[mi] = *(const bf16x8*)(&As[(wm + mi*16 + l15)*40 + l4*8]);
    #pragma unroll
    for (int ni=0;ni<4;++ni)
      b[ni] = *(const bf16x8*)(&Bs[(wn + ni*16 + l15)*40 + l4*8]);
    #pragma unroll
    for (int mi=0;mi<4;++mi)
      #pragma unroll
      for (int ni=0;ni<4;++ni)
        acc[mi][ni] = __builtin_amdgcn_mfma_f32_16x16x32_bf16(a[mi], b[ni], acc[mi][ni], 0,0,0);
  }

  #pragma unroll
  for (int ni=0;ni<4;++ni){
    const int col = n_base + n0 + wn + ni*16 + l15;
    if (col < VOCABq){
      const float bp = b_proj[col];
      #pragma unroll
      for (int mi=0;mi<4;++mi){
        const int rbase = m0 + wm + mi*16 + l4*4;
        #pragma unroll
        for (int r=0;r<4;++r)
          out[(size_t)(rbase+r)*VEXTq + col] = acc[mi][ni][r] + bp;
      }
    }
  }
}

// ---- per-row softmax * p_gen, zero OOV, scatter-add (1-pg)*attn ----
__global__ __launch_bounds__(256) void k_sm(float* __restrict__ out,
    const float* __restrict__ pgen, const float* __restrict__ attn_ws,
    const int* __restrict__ enc_ids){
  __shared__ float redm[4], reds[4];
  const int row=blockIdx.x, tid=threadIdx.x;
  const int b = row & (Bq-1);
  float* orow = out + (size_t)row*VEXTq;
  float m=-1e30f, s=0.f;
  for (int i=tid;i<VOCABq;i+=256){
    float l=orow[i];
    float nm=fmaxf(m,l);
    s = s*__expf(m-nm) + __expf(l-nm);
    m = nm;
  }
  #pragma unroll
  for (int off=32; off>0; off>>=1){
    float om=__shfl_down(m,off), os=__shfl_down(s,off);
    float nm=fmaxf(m,om);
    s = s*__expf(m-nm)+os*__expf(om-nm);
    m = nm;
  }
  int lane=tid&63, wid=tid>>6;
  if (lane==0){ redm[wid]=m; reds[wid]=s; }
  __syncthreads();
  float M=redm[0];
  #pragma unroll
  for (int w=1;w<4;++w) M=fmaxf(M,redm[w]);
  float Ssum=0.f;
  #pragma unroll
  for (int w=0;w<4;++w) Ssum += reds[w]*__expf(redm[w]-M);
  const float pg = pgen[row];
  const float scale = pg/Ssum;
  for (int i=tid;i<VOCABq;i+=256) orow[i]=scale*__expf(orow[i]-M);
  for (int i=VOCABq+tid;i<VEXTq;i+=256) orow[i]=0.f;
  __syncthreads();
  const float w1 = 1.f-pg;
  const float* arow = attn_ws + (size_t)row*Sq;
  const int* ids = enc_ids + b*Sq;
  for (int si=tid; si<Sq; si+=256)
    atomicAdd(&orow[ids[si]], w1*arow[si]);
}

extern "C" void kernel_launch(void* const* d_in, const int* in_sizes, int n_in,
                              void* d_out, int out_size, void* d_ws, size_t ws_size,
                              hipStream_t stream) {
  (void)in_sizes; (void)n_in; (void)out_size; (void)ws_size;
  const int*   dec_ids    = (const int*)  d_in[0];
  const int*   enc_ids    = (const int*)  d_in[1];
  const float* enc_states = (const float*)d_in[2];
  const float* mask       = (const float*)d_in[3];
  const float* init_h     = (const float*)d_in[4];
  const float* init_c     = (const float*)d_in[5];
  const float* embeddings = (const float*)d_in[6];
  const float* W_enc      = (const float*)d_in[7];
  const float* b_enc      = (const float*)d_in[8];
  const float* W_attn     = (const float*)d_in[9];
  const float* vvec       = (const float*)d_in[10];
  const float* w_cov      = (const float*)d_in[11];
  const float* b_cov      = (const float*)d_in[12];
  const float* W_x        = (const float*)d_in[13];
  const float* W_out      = (const float*)d_in[14];
  const float* Wk         = (const float*)d_in[15];
  const float* Wr         = (const float*)d_in[16];
  const float* b_lstm     = (const float*)d_in[17];
  const float* W_pgen     = (const float*)d_in[18];
  const float* W_proj     = (const float*)d_in[19];
  const float* b_proj     = (const float*)d_in[20];
  float* out = (float*)d_out;
  float* ws  = (float*)d_ws;

  float* EF      = ws;                              // 8,388,608
  float* attn_ws = EF      + (size_t)8388608;       //   524,288
  float* hc_ws   = attn_ws + (size_t)524288;        // 1,048,576
  u16*   outm_bf = (u16*)(hc_ws + (size_t)1048576); //   262,144 f32 slots
  float* pgen_ws = hc_ws   + (size_t)1048576 + 262144; //  1,024
  float* embx    = pgen_ws + (size_t)1024;          //   524,288
  float* embxp   = embx    + (size_t)524288;        //     1,024
  float* embz    = embxp   + (size_t)1024;          // 2,097,152
  float* WXKT_   = embz    + (size_t)2097152;       // 1,048,576
  float* WrT_    = WXKT_   + (size_t)1048576;       // 1,048,576
  float* Wxp     = WrT_    + (size_t)1048576;       //       512
  float* Hbuf    = Wxp     + (size_t)512;           //    16,384
  float* Cbuf    = Hbuf    + (size_t)16384;         //    16,384
  float* CtxP    = Cbuf    + (size_t)16384;         //    16,384
  u16*   WT      = (u16*)(CtxP + (size_t)16384);    // 12,845,056 u16

  // ---- precompute ----
  k_enc<<<(Bq*Sq)/16, 512, 0, stream>>>(enc_states, W_enc, b_enc, EF);
  k_embx<<<64, 512, 0, stream>>>(dec_ids, embeddings, W_x, W_pgen, embx, embxp);
  {
    dim3 g(64,4);
    k_embz<<<g, 512, 0, stream>>>(embx, Wk, b_lstm, embz);
  }
  {
    dim3 g(32,16);
    k_wxk<<<g, 512, 0, stream>>>(Wk, W_x, WXKT_);
  }
  {
    dim3 g(64,16);   // WrT: in [512][2048] -> out [2048][512]
    k_trans<<<g, 512, 0, stream>>>(Wr, WrT_, 512, 2048);
  }
  k_wp<<<1, 512, 0, stream>>>(W_x, W_pgen, Wxp);

  // ---- recurrence: one cooperative kernel, 64 grid syncs ----
  {
    void* args[] = { (void*)&EF, (void*)&mask, (void*)&init_h, (void*)&init_c,
                     (void*)&WXKT_, (void*)&WrT_, (void*)&embz, (void*)&embxp,
                     (void*)&W_attn, (void*)&vvec, (void*)&w_cov, (void*)&b_cov,
                     (void*)&W_pgen, (void*)&Wxp,
                     (void*)&Hbuf, (void*)&Cbuf, (void*)&CtxP,
                     (void*)&hc_ws, (void*)&attn_ws, (void*)&pgen_ws };
    hipLaunchCooperativeKernel((void*)k_rec2, dim3(256), dim3(512), args, 0, stream);
  }

  // ---- output projection (bf16 MFMA, two vocab halves) + softmax + scatter ----
  k_mid<<<(Tq*Bq)/16, 512, 0, stream>>>(hc_ws, W_out, outm_bf);
  for (int half=0; half<2; ++half){
    const int n_base = half*HALF_N;
    dim3 gc(HALF_N/32, 16);
    k_wcvt<<<gc, 256, 0, stream>>>(W_proj, WT, n_base);
    dim3 gp(8, HALF_N/128);
    k_projm<<<gp, 256, 0, stream>>>(outm_bf, WT, b_proj, out, n_base);
  }
  k_sm<<<Tq*Bq, 256, 0, stream>>>(out, pgen_ws, attn_ws, enc_ids);
}

// Round 5
// 2836.978 us; speedup vs baseline: 2.5065x; 2.5065x over previous
//
#include <hip/hip_runtime.h>
#include <math.h>

#define Bq 32
#define Sq 512
#define Tq 32
#define EMBq 256
#define HIDq 512
#define VOCABq 50000
#define OOVq 100
#define VEXTq (VOCABq + OOVq)
#define HALF_N 25088

typedef unsigned short u16;
typedef unsigned long long u64;
typedef __attribute__((ext_vector_type(8))) short bf16x8;
typedef __attribute__((ext_vector_type(4))) float f32x4;

__device__ __forceinline__ float sigmoidf_(float x){ return 1.0f/(1.0f+__expf(-x)); }
__device__ __forceinline__ float tanhf_(float x){ return 1.0f - 2.0f/(__expf(2.0f*x)+1.0f); }

__device__ __forceinline__ u16 f2bf(float x){
  union{float f; unsigned u;} v; v.f=x;
  unsigned r = v.u + 0x7FFFu + ((v.u>>16)&1u);
  return (u16)(r>>16);
}
__device__ __forceinline__ float bf2f(u16 h){
  union{unsigned u; float f;} v; v.u = ((unsigned)h)<<16; return v.f;
}

// ---- device-coherent (agent-scope, L2-bypass) accessors for cross-block state ----
__device__ __forceinline__ float ld1(const float* p){
  return __hip_atomic_load((float*)p, __ATOMIC_RELAXED, __HIP_MEMORY_SCOPE_AGENT);
}
__device__ __forceinline__ void st1(float* p, float v){
  __hip_atomic_store(p, v, __ATOMIC_RELAXED, __HIP_MEMORY_SCOPE_AGENT);
}
__device__ __forceinline__ float2 ld2(const float* p){
  u64 v = __hip_atomic_load((u64*)p, __ATOMIC_RELAXED, __HIP_MEMORY_SCOPE_AGENT);
  union{u64 u; float2 f;} c; c.u=v; return c.f;
}
__device__ __forceinline__ void st2(float* p, float a, float b){
  union{u64 u; float2 f;} c; c.f.x=a; c.f.y=b;
  __hip_atomic_store((u64*)p, c.u, __ATOMIC_RELAXED, __HIP_MEMORY_SCOPE_AGENT);
}
// barrier: no cache fences — all shared state goes through sc1 accessors above.
__device__ __forceinline__ void barrier_wait(unsigned* ctr, unsigned target){
  asm volatile("s_waitcnt vmcnt(0)" ::: "memory");   // per-wave store drain
  __syncthreads();
  if (threadIdx.x==0){
    __hip_atomic_fetch_add(ctr, 1u, __ATOMIC_RELAXED, __HIP_MEMORY_SCOPE_AGENT);
    while (__hip_atomic_load(ctr, __ATOMIC_RELAXED, __HIP_MEMORY_SCOPE_AGENT) < target)
      __builtin_amdgcn_s_sleep(2);
  }
  __syncthreads();
}

__device__ __forceinline__ float blockSum512(float v, float* red){
  #pragma unroll
  for (int off=32; off>0; off>>=1) v += __shfl_down(v, off);
  int lane = threadIdx.x & 63, wid = threadIdx.x >> 6;
  __syncthreads();
  if (lane==0) red[wid]=v;
  __syncthreads();
  float t=0.f;
  #pragma unroll
  for (int w=0;w<8;++w) t+=red[w];
  return t;
}

// ---- W_enc [512k][512n] -> WET bf16 [n][k] ----
__global__ __launch_bounds__(256) void k_wet(const float* __restrict__ W, u16* __restrict__ WT){
  __shared__ float T[32][33];
  const int n0 = blockIdx.x*32, k0 = blockIdx.y*32;
  const int tid=threadIdx.x;
  #pragma unroll
  for (int it=0; it<4; ++it){
    int id = tid+it*256; int kk=id>>5, nn=id&31;
    T[kk][nn] = W[(size_t)(k0+kk)*512 + n0+nn];
  }
  __syncthreads();
  #pragma unroll
  for (int it=0; it<4; ++it){
    int id=tid+it*256; int nn=id>>5, kk=id&31;
    WT[(size_t)(n0+nn)*512 + k0+kk] = f2bf(T[kk][nn]);
  }
}

// ---- EFbf = bf16( es @ W_enc + b_enc ), MFMA ----
__global__ __launch_bounds__(256) void k_encm(const float* __restrict__ es,
    const u16* __restrict__ WET, const float* __restrict__ b_enc,
    u16* __restrict__ EFbf){
  __shared__ u16 As[128*40];
  __shared__ u16 Bs[128*40];
  const int tid=threadIdx.x;
  const int m0 = blockIdx.x*128, n0 = blockIdx.y*128;
  const int wid=tid>>6, lane=tid&63;
  const int wm=(wid>>1)*64, wn=(wid&1)*64;
  const int l15=lane&15, l4=lane>>4;
  f32x4 acc[4][4];
  #pragma unroll
  for (int mi=0;mi<4;++mi)
    #pragma unroll
    for (int ni=0;ni<4;++ni) acc[mi][ni] = (f32x4){0.f,0.f,0.f,0.f};
  for (int kt=0; kt<16; ++kt){
    const int k0=kt*32;
    __syncthreads();
    #pragma unroll
    for (int it=0; it<4; ++it){
      int id=tid+it*256; int row=id>>3, q=id&7;
      float4 v = *(const float4*)(es + (size_t)(m0+row)*512 + k0 + q*4);
      u64 pk = (u64)f2bf(v.x) | ((u64)f2bf(v.y)<<16) | ((u64)f2bf(v.z)<<32) | ((u64)f2bf(v.w)<<48);
      *(u64*)&As[row*40 + q*4] = pk;
    }
    #pragma unroll
    for (int it=0; it<2; ++it){
      int id=tid+it*256; int row=id>>2, c4=id&3;
      uint4 v = *(const uint4*)(WET + (size_t)(n0+row)*512 + k0 + c4*8);
      *(uint4*)&Bs[row*40 + c4*8] = v;
    }
    __syncthreads();
    bf16x8 a[4], b[4];
    #pragma unroll
    for (int mi=0;mi<4;++mi) a[mi] = *(const bf16x8*)(&As[(wm+mi*16+l15)*40 + l4*8]);
    #pragma unroll
    for (int ni=0;ni<4;++ni) b[ni] = *(const bf16x8*)(&Bs[(wn+ni*16+l15)*40 + l4*8]);
    #pragma unroll
    for (int mi=0;mi<4;++mi)
      #pragma unroll
      for (int ni=0;ni<4;++ni)
        acc[mi][ni] = __builtin_amdgcn_mfma_f32_16x16x32_bf16(a[mi], b[ni], acc[mi][ni], 0,0,0);
  }
  #pragma unroll
  for (int ni=0;ni<4;++ni){
    const int col = n0+wn+ni*16+l15;
    const float bp = b_enc[col];
    #pragma unroll
    for (int mi=0;mi<4;++mi){
      const int rb = m0+wm+mi*16+l4*4;
      #pragma unroll
      for (int r=0;r<4;++r)
        EFbf[(size_t)(rb+r)*512 + col] = f2bf(acc[mi][ni][r]+bp);
    }
  }
}

// ---- embx + embxp ----
__global__ __launch_bounds__(512) void k_embx(const int* __restrict__ dec_ids,
  const float* __restrict__ emb, const float* __restrict__ W_x,
  const float* __restrict__ Wpgen, float* __restrict__ embx, float* __restrict__ embxp){
  __shared__ float A[16][257];
  __shared__ int ids[16];
  __shared__ float red[8];
  const int tid = threadIdx.x, r0 = blockIdx.x*16;
  if (tid<16){
    int row = r0+tid, tt = row>>5, bb = row&31;
    ids[tid] = dec_ids[bb*Tq + tt];
  }
  __syncthreads();
  for (int idx=tid; idx<16*256; idx+=512){
    int rr = idx>>8, kk = idx&255;
    A[rr][kk] = emb[(size_t)ids[rr]*EMBq + kk];
  }
  __syncthreads();
  float acc[16];
  #pragma unroll
  for (int r=0;r<16;++r) acc[r]=0.f;
  for (int k=0;k<256;++k){
    float w = W_x[(size_t)k*HIDq + tid];
    #pragma unroll
    for (int r=0;r<16;++r) acc[r] += A[r][k]*w;
  }
  float wp4 = Wpgen[1536+tid];
  for (int r=0;r<16;++r){
    embx[(size_t)(r0+r)*HIDq + tid] = acc[r];
    float s = blockSum512(acc[r]*wp4, red);
    if (tid==0) embxp[r0+r] = s;
  }
}

// ---- embz = embx @ Wk + b_lstm ----
__global__ __launch_bounds__(512) void k_embz(const float* __restrict__ embx,
  const float* __restrict__ Wk, const float* __restrict__ b_lstm, float* __restrict__ embz){
  __shared__ float A[16][513];
  const int tid = threadIdx.x;
  const int r0 = blockIdx.x*16;
  const int n  = blockIdx.y*512 + tid;
  for (int idx=tid; idx<16*512; idx+=512){
    int rr=idx>>9, kk=idx&511;
    A[rr][kk] = embx[(size_t)(r0+rr)*HIDq + kk];
  }
  __syncthreads();
  float acc[16];
  #pragma unroll
  for (int r=0;r<16;++r) acc[r]=0.f;
  for (int k=0;k<512;++k){
    float w = Wk[(size_t)k*2048 + n];
    #pragma unroll
    for (int r=0;r<16;++r) acc[r] += A[r][k]*w;
  }
  float bl = b_lstm[n];
  #pragma unroll
  for (int r=0;r<16;++r) embz[(size_t)(r0+r)*2048 + n] = acc[r]+bl;
}

// ---- WXKT[n][j] = sum_i Wk[i][n] * W_x[256+j][i] ----
__global__ __launch_bounds__(512) void k_wxk(const float* __restrict__ Wk,
    const float* __restrict__ W_x, float* __restrict__ WXKT_){
  __shared__ float KT[32][64];
  __shared__ float X2[32][33];
  const int tid = threadIdx.x;
  const int n0 = blockIdx.x * 64;
  const int j0 = blockIdx.y * 32;
  const int jj = tid & 31;
  const int ng = tid >> 5;
  float acc[4] = {0,0,0,0};
  for (int i0=0;i0<512;i0+=32){
    __syncthreads();
    for (int idx=tid; idx<32*64; idx+=512){
      int ii = idx>>6, nn = idx&63;
      KT[ii][nn] = Wk[(size_t)(i0+ii)*2048 + n0+nn];
    }
    for (int idx=tid; idx<32*32; idx+=512){
      int j2 = idx>>5, i2 = idx&31;
      X2[j2][i2] = W_x[(size_t)(256+j0+j2)*HIDq + i0+i2];
    }
    __syncthreads();
    for (int ii=0;ii<32;++ii){
      float xv = X2[jj][ii];
      #pragma unroll
      for (int q=0;q<4;++q) acc[q] += KT[ii][ng*4+q]*xv;
    }
  }
  #pragma unroll
  for (int q=0;q<4;++q) WXKT_[(size_t)(n0+ng*4+q)*512 + j0+jj] = acc[q];
}

// ---- 32x32 transpose ----
__global__ __launch_bounds__(512) void k_trans(const float* __restrict__ in,
    float* __restrict__ out, int K, int N){
  __shared__ float T[32][33];
  const int n0 = blockIdx.x*32, k0 = blockIdx.y*32;
  const int tid = threadIdx.x;
  for (int idx=tid; idx<1024; idx+=512){
    int kk = idx>>5, nn = idx&31;
    T[kk][nn] = in[(size_t)(k0+kk)*N + n0+nn];
  }
  __syncthreads();
  for (int idx=tid; idx<1024; idx+=512){
    int nn = idx>>5, kk = idx&31;
    out[(size_t)(n0+nn)*K + k0+kk] = T[kk][nn];
  }
}

// ---- WGbf[col*4+g][k] = bf16( k<512 ? WXKT[g*512+col][k] : WrT[g*512+col][k-512] ) ----
__global__ __launch_bounds__(512) void k_wgcvt(const float* __restrict__ WXKT_,
    const float* __restrict__ WrT_, u16* __restrict__ WGbf){
  const int np = blockIdx.x;
  const int col = np>>2, g = np&3;
  const int n = g*512 + col;
  const float* s1 = WXKT_ + (size_t)n*512;
  const float* s2 = WrT_  + (size_t)n*512;
  u16* o = WGbf + (size_t)np*1024;
  int k = threadIdx.x;
  o[k]     = f2bf(s1[k]);
  o[512+k] = f2bf(s2[k]);
}

// ---- generic f32 -> bf16 copy ----
__global__ void k_cvt(const float* __restrict__ in, u16* __restrict__ out, int n){
  int i = blockIdx.x*256 + threadIdx.x;
  if (i<n) out[i] = f2bf(in[i]);
}

// ---- Wxp[j] = sum_i W_x[256+j][i]*W_pgen[1536+i] ----
__global__ __launch_bounds__(512) void k_wp(const float* __restrict__ W_x,
  const float* __restrict__ Wpgen, float* __restrict__ Wxp){
  int j = threadIdx.x;
  const float* row = W_x + (size_t)(256+j)*HIDq;
  float s=0.f;
  for (int i=0;i<512;++i) s += row[i]*Wpgen[1536+i];
  Wxp[j] = s;
}

// ==== persistent recurrence, custom barriers, sc1 state, L2-resident weights ====
// grid 256 x 512 (1 block/CU). Phase A: blocks 0..31 MFMA gates (n'-chunks of 64,
// n' = col*4+gate). Phase B: block (b=bid>>3, sc=bid&7): df-slice -> minibar ->
// e-pass -> stats -> cp -> minibar -> ctx/pgen finalize. attn/cov finalized next step.
__global__ __launch_bounds__(512,1) void k_rec3(
  const u16* __restrict__ EFbf, const float* __restrict__ mask,
  const float* __restrict__ init_h, const float* __restrict__ init_c,
  const u16* __restrict__ WGbf, const float* __restrict__ embz,
  const u16* __restrict__ WAbf, const float* __restrict__ vvec,
  const float* __restrict__ wcov, const float* __restrict__ bcov,
  const float* __restrict__ Wpgen, const float* __restrict__ Wxp,
  float* __restrict__ Hbuf, float* __restrict__ Cbuf, float* __restrict__ Ctx,
  float* __restrict__ dfg, float* __restrict__ mZ, float* __restrict__ cp,
  float* __restrict__ hc_ws, float* __restrict__ attn_ws, float* __restrict__ pgen_raw,
  unsigned* __restrict__ gcnt, unsigned* __restrict__ bcnt)
{
  __shared__ float cbuf[512];            // A-persistent: c registers
  __shared__ float covb[64], eprev[64];  // B-persistent
  __shared__ float mzl[16];
  __shared__ union {
    struct { u16 XA[32*1032]; float zbuf[32*64]; } a;
    struct { float hb[512], cb[512], dfl[512]; float dfpart[8][64]; float el[64], wl[64]; } b;
  } u;

  const int tid = threadIdx.x, bid = blockIdx.x;
  const int lane = tid&63, wv = tid>>6;
  const int bB = bid>>3, sc = bid&7, s0 = sc*64;
  const int j0 = lane*8;
  const int l15 = lane&15, l4 = lane>>4;
  const int mtile = wv>>2, ntile = wv&3;

  float vvr[8], wcr[8], bcr[8];
  *(float4*)&vvr[0] = *(const float4*)&vvec[j0]; *(float4*)&vvr[4] = *(const float4*)&vvec[j0+4];
  *(float4*)&wcr[0] = *(const float4*)&wcov[j0]; *(float4*)&wcr[4] = *(const float4*)&wcov[j0+4];
  *(float4*)&bcr[0] = *(const float4*)&bcov[j0]; *(float4*)&bcr[4] = *(const float4*)&bcov[j0+4];

  if (bid<32){
    int b = tid>>4, cl = tid&15, colg = bid*16+cl;
    cbuf[tid] = init_c[b*512+colg];
  }

  unsigned gt = 0, mt = 0;

  for (int t=0; t<Tq; ++t){
    // ================= PHASE A: gates + LSTM (blocks 0..31) =================
    if (bid < 32){
      const float* Hprev = Hbuf + ((t+1)&1)*16384;
      for (int p = tid; p < 16384; p += 512){
        int e2 = p*2, b = e2>>10, k = e2&1023;
        float2 f;
        if (t==0){
          if (k<512){ f.x=0.f; f.y=0.f; }
          else f = *(const float2*)(init_h + b*512 + (k-512));
        } else {
          f = (k<512) ? ld2(Ctx + b*512 + k) : ld2(Hprev + b*512 + (k-512));
        }
        unsigned pk = (unsigned)f2bf(f.x) | ((unsigned)f2bf(f.y)<<16);
        *(unsigned*)&u.a.XA[b*1032 + k] = pk;
      }
      __syncthreads();
      f32x4 acc = {0.f,0.f,0.f,0.f};
      const u16* Brow = WGbf + (size_t)(bid*64 + ntile*16 + l15)*1024 + l4*8;
      const u16* Arow = &u.a.XA[(mtile*16 + l15)*1032 + l4*8];
      #pragma unroll 4
      for (int kk=0; kk<32; ++kk){
        bf16x8 af = *(const bf16x8*)(Arow + kk*32);
        bf16x8 bf = *(const bf16x8*)(Brow + kk*32);
        acc = __builtin_amdgcn_mfma_f32_16x16x32_bf16(af, bf, acc, 0,0,0);
      }
      __syncthreads();
      #pragma unroll
      for (int r=0;r<4;++r)
        u.a.zbuf[(mtile*16 + l4*4 + r)*64 + ntile*16 + l15] = acc[r];
      __syncthreads();
      {
        int b = tid>>4, cl = tid&15, colg = bid*16+cl;
        const float* ez = embz + ((size_t)t*Bq + b)*2048 + colg;
        float zi = u.a.zbuf[b*64 + cl*4+0] + ez[0];
        float zf = u.a.zbuf[b*64 + cl*4+1] + ez[512];
        float zg = u.a.zbuf[b*64 + cl*4+2] + ez[1024];
        float zo = u.a.zbuf[b*64 + cl*4+3] + ez[1536];
        float co = cbuf[tid];
        float cn = sigmoidf_(zf)*co + sigmoidf_(zi)*tanhf_(zg);
        float hn = sigmoidf_(zo)*tanhf_(cn);
        cbuf[tid] = cn;
        st1(Cbuf + b*512+colg, cn);
        st1(Hbuf + (t&1)*16384 + b*512+colg, hn);
        hc_ws[((size_t)t*Bq+b)*1024 + colg] = hn;
      }
    }
    gt += 256; barrier_wait(gcnt, gt);
    // ================= PHASE B: attention (all 256 blocks) =================
    // (1) finalize attn/cov of step t-1
    if (t > 0){
      if (tid<16) mzl[tid] = ld1(mZ + (bB*8+(tid>>1))*2 + (tid&1));
      __syncthreads();
      float M = mzl[0];
      #pragma unroll
      for (int l=1;l<8;++l) M = fmaxf(M, mzl[l*2]);
      float D = 0.f;
      #pragma unroll
      for (int l=0;l<8;++l) D += __expf(mzl[l*2]-M)*mzl[l*2+1];
      if (tid<64){
        float a = mask[bB*512+s0+tid]*__expf(eprev[tid]-M)/D;
        attn_ws[((size_t)(t-1)*Bq+bB)*Sq + s0+tid] = a;
        covb[tid] = (t==1) ? a : covb[tid]+a;
      }
      __syncthreads();
    }
    // (2) stage h_t, c_t; df-slice
    if (tid<256){
      float2 f = ld2(Hbuf + (t&1)*16384 + bB*512 + tid*2);
      u.b.hb[tid*2]=f.x; u.b.hb[tid*2+1]=f.y;
    } else {
      int q = tid-256;
      float2 f = ld2(Cbuf + bB*512 + q*2);
      u.b.cb[q*2]=f.x; u.b.cb[q*2+1]=f.y;
    }
    __syncthreads();
    {
      const float* xs = (wv<4) ? &u.b.hb[wv*128] : &u.b.cb[(wv-4)*128];
      const u16* wa = WAbf + (size_t)(wv*128)*512 + s0 + lane;
      float acc = 0.f;
      #pragma unroll 4
      for (int k=0;k<128;++k) acc += xs[k]*bf2f(wa[(size_t)k*512]);
      u.b.dfpart[wv][lane] = acc;
    }
    __syncthreads();
    if (tid<64){
      float d = 0.f;
      #pragma unroll
      for (int w=0;w<8;++w) d += u.b.dfpart[w][tid];
      st1(dfg + bB*512 + s0 + tid, d);
    }
    mt += 8; barrier_wait(bcnt + bB, mt);
    // (4) full df; e-pass over 64 s-rows
    if (tid<256){
      float2 f = ld2(dfg + bB*512 + tid*2);
      u.b.dfl[tid*2]=f.x; u.b.dfl[tid*2+1]=f.y;
    }
    __syncthreads();
    {
      float dd[8];
      *(float4*)&dd[0] = *(const float4*)&u.b.dfl[j0];
      *(float4*)&dd[4] = *(const float4*)&u.b.dfl[j0+4];
      const u16* efb = EFbf + ((size_t)(bB*512 + s0))*512;
      for (int r=0;r<8;++r){
        int sl = wv*8 + r;
        uint4 pack = *(const uint4*)(efb + (size_t)sl*512 + j0);
        const u16* ph = (const u16*)&pack;
        float a8 = 0.f;
        if (t>0){
          float cvs = covb[sl];
          #pragma unroll
          for (int q=0;q<8;++q) a8 += vvr[q]*tanhf_(bf2f(ph[q])+dd[q]+cvs*wcr[q]+bcr[q]);
        } else {
          #pragma unroll
          for (int q=0;q<8;++q) a8 += vvr[q]*tanhf_(bf2f(ph[q])+dd[q]);
        }
        #pragma unroll
        for (int off=32; off>0; off>>=1) a8 += __shfl_down(a8, off);
        if (lane==0) u.b.el[sl] = a8;
      }
    }
    __syncthreads();
    // (5) chunk softmax stats
    if (tid<64){
      float e = u.b.el[tid];
      float m = e;
      #pragma unroll
      for (int off=32; off>0; off>>=1) m = fmaxf(m, __shfl_xor(m, off));
      float w_ = mask[bB*512+s0+tid]*__expf(e-m);
      float Z = w_;
      #pragma unroll
      for (int off=32; off>0; off>>=1) Z += __shfl_xor(Z, off);
      u.b.wl[tid] = w_;
      eprev[tid] = e;
      if (tid==0) st2(mZ + (bB*8+sc)*2, m, Z);
    }
    __syncthreads();
    // (6) cp-pass: unnormalized ctx partial
    {
      float acc = 0.f;
      const u16* efc = EFbf + ((size_t)(bB*512+s0))*512 + tid;
      #pragma unroll 4
      for (int s=0;s<64;++s) acc += u.b.wl[s]*bf2f(efc[(size_t)s*512]);
      st1(cp + ((size_t)(bB*8+sc))*512 + tid, acc);
    }
    mt += 8; barrier_wait(bcnt + bB, mt);
    // (8) finalize ctx + pgen
    if (tid<16) mzl[tid] = ld1(mZ + (bB*8+(tid>>1))*2 + (tid&1));
    __syncthreads();
    {
      float M = mzl[0];
      #pragma unroll
      for (int l=1;l<8;++l) M = fmaxf(M, mzl[l*2]);
      float D = 0.f;
      #pragma unroll
      for (int l=0;l<8;++l) D += __expf(mzl[l*2]-M)*mzl[l*2+1];
      if (tid<64){
        int j = s0 + tid;
        float cold = ld1(Ctx + bB*512 + j);
        float cx = 0.f;
        #pragma unroll
        for (int l=0;l<8;++l) cx += __expf(mzl[l*2]-M)*ld1(cp + ((size_t)(bB*8+l))*512 + j);
        cx /= D;
        st1(Ctx + bB*512 + j, cx);
        hc_ws[((size_t)t*Bq+bB)*1024 + 512 + j] = cx;
        float part = cx*Wpgen[j] + u.b.hb[j]*Wpgen[512+j]
                   + u.b.cb[j]*Wpgen[1024+j] + cold*Wxp[j];
        #pragma unroll
        for (int off=32; off>0; off>>=1) part += __shfl_down(part, off);
        if (tid==0)
          __hip_atomic_fetch_add(pgen_raw + t*Bq + bB, part, __ATOMIC_RELAXED, __HIP_MEMORY_SCOPE_AGENT);
      }
    }
    gt += 256; barrier_wait(gcnt, gt);
  }
  // epilogue: attn for t = Tq-1
  {
    if (tid<16) mzl[tid] = ld1(mZ + (bB*8+(tid>>1))*2 + (tid&1));
    __syncthreads();
    float M = mzl[0];
    #pragma unroll
    for (int l=1;l<8;++l) M = fmaxf(M, mzl[l*2]);
    float D = 0.f;
    #pragma unroll
    for (int l=0;l<8;++l) D += __expf(mzl[l*2]-M)*mzl[l*2+1];
    if (tid<64){
      float a = mask[bB*512+s0+tid]*__expf(eprev[tid]-M)/D;
      attn_ws[((size_t)(Tq-1)*Bq+bB)*Sq + s0+tid] = a;
    }
  }
}

// ---- OUTm = [h,ctx] @ W_out -> bf16 ----
__global__ __launch_bounds__(512) void k_mid(const float* __restrict__ hc,
    const float* __restrict__ W_out, u16* __restrict__ outm_bf){
  __shared__ float A[16][256];
  const int tid=threadIdx.x;
  const int r0=blockIdx.x*16;
  float acc[16];
  #pragma unroll
  for (int r=0;r<16;++r) acc[r]=0.f;
  for (int kc=0;kc<4;++kc){
    __syncthreads();
    for (int i=tid;i<16*256;i+=512){
      int rr=i>>8, kk=i&255;
      A[rr][kk]=hc[(size_t)(r0+rr)*1024 + kc*256+kk];
    }
    __syncthreads();
    for (int k=0;k<256;++k){
      float w=W_out[(size_t)(kc*256+k)*HIDq + tid];
      #pragma unroll
      for (int r=0;r<16;++r) acc[r]+=A[r][k]*w;
    }
  }
  #pragma unroll
  for (int r=0;r<16;++r) outm_bf[(size_t)(r0+r)*HIDq+tid]=f2bf(acc[r]);
}

// ---- W_proj f32 [512][50000] -> WT bf16 [HALF_N][512] ----
__global__ __launch_bounds__(256) void k_wcvt(const float* __restrict__ Wp,
    u16* __restrict__ WT, int n_base){
  __shared__ float T[32][33];
  const int n0 = blockIdx.x*32, k0 = blockIdx.y*32;
  const int tid = threadIdx.x;
  #pragma unroll
  for (int it=0; it<4; ++it){
    int id = tid + it*256;
    int kk = id>>5, nn = id&31;
    int gn = n_base + n0 + nn;
    T[kk][nn] = (gn < VOCABq) ? Wp[(size_t)(k0+kk)*VOCABq + gn] : 0.f;
  }
  __syncthreads();
  #pragma unroll
  for (int it=0; it<4; ++it){
    int id = tid + it*256;
    int nn = id>>5, kk = id&31;
    WT[(size_t)(n0+nn)*512 + k0+kk] = f2bf(T[kk][nn]);
  }
}

// ---- logits = Abf @ WT^T + b_proj -> d_out rows ----
__global__ __launch_bounds__(256) void k_projm(const u16* __restrict__ Abf,
    const u16* __restrict__ WT, const float* __restrict__ b_proj,
    float* __restrict__ out, int n_base){
  __shared__ u16 As[128*40];
  __shared__ u16 Bs[128*40];
  const int tid = threadIdx.x;
  const int m0 = blockIdx.x * 128;
  const int n0 = blockIdx.y * 128;
  const int wid = tid>>6, lane = tid&63;
  const int wm = (wid>>1)*64, wn = (wid&1)*64;
  const int l15 = lane&15, l4 = lane>>4;
  f32x4 acc[4][4];
  #pragma unroll
  for (int mi=0;mi<4;++mi)
    #pragma unroll
    for (int ni=0;ni<4;++ni) acc[mi][ni] = (f32x4){0.f,0.f,0.f,0.f};

  for (int kt=0; kt<16; ++kt){
    const int k0 = kt*32;
    __syncthreads();
    #pragma unroll
    for (int it=0; it<2; ++it){
      int id = tid + it*256;
      int row = id>>2, c4 = id&3;
      uint4 va = *(const uint4*)(Abf + (size_t)(m0+row)*512 + k0 + c4*8);
      *(uint4*)(&As[row*40 + c4*8]) = va;
      uint4 vb = *(const uint4*)(WT + (size_t)(n0+row)*512 + k0 + c4*8);
      *(uint4*)(&Bs[row*40 + c4*8]) = vb;
    }
    __syncthreads();
    bf16x8 a[4], b[4];
    #pragma unroll
    for (int mi=0;mi<4;++mi)
      a[mi] = *(const bf16x8*)(&As[(wm + mi*16 + l15)*40 + l4*8]);
    #pragma unroll
    for (int ni=0;ni<4;++ni)
      b[ni] = *(const bf16x8*)(&Bs[(wn + ni*16 + l15)*40 + l4*8]);
    #pragma unroll
    for (int mi=0;mi<4;++mi)
      #pragma unroll
      for (int ni=0;ni<4;++ni)
        acc[mi][ni] = __builtin_amdgcn_mfma_f32_16x16x32_bf16(a[mi], b[ni], acc[mi][ni], 0,0,0);
  }

  #pragma unroll
  for (int ni=0;ni<4;++ni){
    const int col = n_base + n0 + wn + ni*16 + l15;
    if (col < VOCABq){
      const float bp = b_proj[col];
      #pragma unroll
      for (int mi=0;mi<4;++mi){
        const int rbase = m0 + wm + mi*16 + l4*4;
        #pragma unroll
        for (int r=0;r<4;++r)
          out[(size_t)(rbase+r)*VEXTq + col] = acc[mi][ni][r] + bp;
      }
    }
  }
}

// ---- per-row softmax * p_gen, zero OOV, scatter-add (1-pg)*attn ----
__global__ __launch_bounds__(256) void k_sm(float* __restrict__ out,
    const float* __restrict__ pgen_raw, const float* __restrict__ embxp,
    const float* __restrict__ attn_ws, const int* __restrict__ enc_ids){
  __shared__ float redm[4], reds[4];
  const int row=blockIdx.x, tid=threadIdx.x;
  const int b = row & (Bq-1);
  float* orow = out + (size_t)row*VEXTq;
  float m=-1e30f, s=0.f;
  for (int i=tid;i<VOCABq;i+=256){
    float l=orow[i];
    float nm=fmaxf(m,l);
    s = s*__expf(m-nm) + __expf(l-nm);
    m = nm;
  }
  #pragma unroll
  for (int off=32; off>0; off>>=1){
    float om=__shfl_down(m,off), os=__shfl_down(s,off);
    float nm=fmaxf(m,om);
    s = s*__expf(m-nm)+os*__expf(om-nm);
    m = nm;
  }
  int lane=tid&63, wid=tid>>6;
  if (lane==0){ redm[wid]=m; reds[wid]=s; }
  __syncthreads();
  float M=redm[0];
  #pragma unroll
  for (int w=1;w<4;++w) M=fmaxf(M,redm[w]);
  float Ssum=0.f;
  #pragma unroll
  for (int w=0;w<4;++w) Ssum += reds[w]*__expf(redm[w]-M);
  const float pg = sigmoidf_(pgen_raw[row] + embxp[row]);
  const float scale = pg/Ssum;
  for (int i=tid;i<VOCABq;i+=256) orow[i]=scale*__expf(orow[i]-M);
  for (int i=VOCABq+tid;i<VEXTq;i+=256) orow[i]=0.f;
  __syncthreads();
  const float w1 = 1.f-pg;
  const float* arow = attn_ws + (size_t)row*Sq;
  const int* ids = enc_ids + b*Sq;
  for (int si=tid; si<Sq; si+=256)
    atomicAdd(&orow[ids[si]], w1*arow[si]);
}

extern "C" void kernel_launch(void* const* d_in, const int* in_sizes, int n_in,
                              void* d_out, int out_size, void* d_ws, size_t ws_size,
                              hipStream_t stream) {
  (void)in_sizes; (void)n_in; (void)out_size; (void)ws_size;
  const int*   dec_ids    = (const int*)  d_in[0];
  const int*   enc_ids    = (const int*)  d_in[1];
  const float* enc_states = (const float*)d_in[2];
  const float* mask       = (const float*)d_in[3];
  const float* init_h     = (const float*)d_in[4];
  const float* init_c     = (const float*)d_in[5];
  const float* embeddings = (const float*)d_in[6];
  const float* W_enc      = (const float*)d_in[7];
  const float* b_enc      = (const float*)d_in[8];
  const float* W_attn     = (const float*)d_in[9];
  const float* vvec       = (const float*)d_in[10];
  const float* w_cov      = (const float*)d_in[11];
  const float* b_cov      = (const float*)d_in[12];
  const float* W_x        = (const float*)d_in[13];
  const float* W_out      = (const float*)d_in[14];
  const float* Wk         = (const float*)d_in[15];
  const float* Wr         = (const float*)d_in[16];
  const float* b_lstm     = (const float*)d_in[17];
  const float* W_pgen     = (const float*)d_in[18];
  const float* W_proj     = (const float*)d_in[19];
  const float* b_proj     = (const float*)d_in[20];
  float* out = (float*)d_out;
  float* ws  = (float*)d_ws;

  u16*   EFbf    = (u16*)ws;                          // 8,388,608 u16
  float* attn_ws = ws + 4194304;
  float* hc_ws   = attn_ws + 524288;
  u16*   outm_bf = (u16*)(hc_ws + 1048576);           // 524,288 u16
  float* embx    = hc_ws + 1048576 + 262144;
  float* embxp   = embx + 524288;
  float* embz    = embxp + 1024;
  float* WXKT_   = embz + 2097152;
  float* WrT_    = WXKT_ + 1048576;
  float* Wxp     = WrT_ + 1048576;
  float* Hbuf    = Wxp + 512;                         // 2 x 16384
  float* Cbuf    = Hbuf + 32768;
  float* CtxP    = Cbuf + 16384;
  float* dfg     = CtxP + 16384;
  float* mZ      = dfg + 16384;
  float* cp      = mZ + 512;
  u16*   WGbf    = (u16*)(cp + 131072);               // 2,097,152 u16
  u16*   WAbf    = (u16*)(((float*)WGbf) + 1048576);  // 524,288 u16
  u16*   WET     = (u16*)(((float*)WAbf) + 262144);   // 262,144 u16
  unsigned* gcnt = (unsigned*)(((float*)WET) + 131072);
  unsigned* bcnt = gcnt + 16;                         // 32 counters (pad to 64 u32)
  float* pgen_raw= (float*)(gcnt + 64);               // 1024
  u16*   WT      = (u16*)(pgen_raw + 1024);           // 12,845,056 u16

  // zero barrier counters + pgen accumulators
  hipMemsetAsync(gcnt, 0, (64 + 1024)*sizeof(unsigned), stream);

  // ---- precompute ----
  {
    dim3 g(16,16);
    k_wet<<<g, 256, 0, stream>>>(W_enc, WET);
  }
  {
    dim3 g(128,4);
    k_encm<<<g, 256, 0, stream>>>(enc_states, WET, b_enc, EFbf);
  }
  k_embx<<<64, 512, 0, stream>>>(dec_ids, embeddings, W_x, W_pgen, embx, embxp);
  {
    dim3 g(64,4);
    k_embz<<<g, 512, 0, stream>>>(embx, Wk, b_lstm, embz);
  }
  {
    dim3 g(32,16);
    k_wxk<<<g, 512, 0, stream>>>(Wk, W_x, WXKT_);
  }
  {
    dim3 g(64,16);   // Wr [512][2048] -> WrT [2048][512]
    k_trans<<<g, 512, 0, stream>>>(Wr, WrT_, 512, 2048);
  }
  k_wgcvt<<<2048, 512, 0, stream>>>(WXKT_, WrT_, WGbf);
  k_cvt<<<(524288+255)/256, 256, 0, stream>>>(W_attn, WAbf, 524288);
  k_wp<<<1, 512, 0, stream>>>(W_x, W_pgen, Wxp);

  // ---- recurrence: persistent kernel, custom barriers ----
  {
    void* args[] = { (void*)&EFbf, (void*)&mask, (void*)&init_h, (void*)&init_c,
                     (void*)&WGbf, (void*)&embz, (void*)&WAbf, (void*)&vvec,
                     (void*)&w_cov, (void*)&b_cov, (void*)&W_pgen, (void*)&Wxp,
                     (void*)&Hbuf, (void*)&Cbuf, (void*)&CtxP,
                     (void*)&dfg, (void*)&mZ, (void*)&cp,
                     (void*)&hc_ws, (void*)&attn_ws, (void*)&pgen_raw,
                     (void*)&gcnt, (void*)&bcnt };
    hipLaunchCooperativeKernel((void*)k_rec3, dim3(256), dim3(512), args, 0, stream);
  }

  // ---- output projection + softmax + scatter ----
  k_mid<<<(Tq*Bq)/16, 512, 0, stream>>>(hc_ws, W_out, outm_bf);
  for (int half=0; half<2; ++half){
    const int n_base = half*HALF_N;
    dim3 gc(HALF_N/32, 16);
    k_wcvt<<<gc, 256, 0, stream>>>(W_proj, WT, n_base);
    dim3 gp(8, HALF_N/128);
    k_projm<<<gp, 256, 0, stream>>>(outm_bf, WT, b_proj, out, n_base);
  }
  k_sm<<<Tq*Bq, 256, 0, stream>>>(out, pgen_raw, embxp, attn_ws, enc_ids);
}

// Round 6
// 2708.840 us; speedup vs baseline: 2.6250x; 1.0473x over previous
//
#include <hip/hip_runtime.h>
#include <math.h>

#define Bq 32
#define Sq 512
#define Tq 32
#define EMBq 256
#define HIDq 512
#define VOCABq 50000
#define OOVq 100
#define VEXTq (VOCABq + OOVq)
#define HALF_N 25088

typedef unsigned short u16;
typedef unsigned long long u64;
typedef __attribute__((ext_vector_type(8))) short bf16x8;
typedef __attribute__((ext_vector_type(4))) float f32x4;

__device__ __forceinline__ float sigmoidf_(float x){ return 1.0f/(1.0f+__expf(-x)); }
__device__ __forceinline__ float tanhf_(float x){ return 1.0f - 2.0f/(__expf(2.0f*x)+1.0f); }

__device__ __forceinline__ u16 f2bf(float x){
  union{float f; unsigned u;} v; v.f=x;
  unsigned r = v.u + 0x7FFFu + ((v.u>>16)&1u);
  return (u16)(r>>16);
}
__device__ __forceinline__ float bf2f(u16 h){
  union{unsigned u; float f;} v; v.u = ((unsigned)h)<<16; return v.f;
}

// ---- agent-scope (L2-bypass, device-coherent) accessors ----
__device__ __forceinline__ float ld1(const float* p){
  return __hip_atomic_load((float*)p, __ATOMIC_RELAXED, __HIP_MEMORY_SCOPE_AGENT);
}
__device__ __forceinline__ void st1(float* p, float v){
  __hip_atomic_store(p, v, __ATOMIC_RELAXED, __HIP_MEMORY_SCOPE_AGENT);
}
__device__ __forceinline__ float2 ld2(const float* p){
  u64 v = __hip_atomic_load((u64*)p, __ATOMIC_RELAXED, __HIP_MEMORY_SCOPE_AGENT);
  union{u64 u; float2 f;} c; c.u=v; return c.f;
}
__device__ __forceinline__ void st2(float* p, float a, float b){
  union{u64 u; float2 f;} c; c.f.x=a; c.f.y=b;
  __hip_atomic_store((u64*)p, c.u, __ATOMIC_RELAXED, __HIP_MEMORY_SCOPE_AGENT);
}

// ---- group-local barrier: 8 blocks, distributed slots, no atomic contention ----
__device__ __forceinline__ void mbar(unsigned* gs, int sc, unsigned tag){
  asm volatile("s_waitcnt vmcnt(0)" ::: "memory");   // drain this wave's stores
  __syncthreads();
  if (threadIdx.x==0)
    __hip_atomic_store(gs+sc, tag, __ATOMIC_RELAXED, __HIP_MEMORY_SCOPE_AGENT);
  if (threadIdx.x<64){
    for(;;){
      unsigned v = (threadIdx.x<8)
        ? __hip_atomic_load(gs+threadIdx.x, __ATOMIC_RELAXED, __HIP_MEMORY_SCOPE_AGENT)
        : tag;
      if (__all(v>=tag)) break;
      __builtin_amdgcn_s_sleep(1);
    }
  }
  __syncthreads();
}

__device__ __forceinline__ float blockSum512(float v, float* red){
  #pragma unroll
  for (int off=32; off>0; off>>=1) v += __shfl_down(v, off);
  int lane = threadIdx.x & 63, wid = threadIdx.x >> 6;
  __syncthreads();
  if (lane==0) red[wid]=v;
  __syncthreads();
  float t=0.f;
  #pragma unroll
  for (int w=0;w<8;++w) t+=red[w];
  return t;
}

// ---- W_enc [512k][512n] -> WET bf16 [n][k] ----
__global__ __launch_bounds__(256) void k_wet(const float* __restrict__ W, u16* __restrict__ WT){
  __shared__ float T[32][33];
  const int n0 = blockIdx.x*32, k0 = blockIdx.y*32;
  const int tid=threadIdx.x;
  #pragma unroll
  for (int it=0; it<4; ++it){
    int id = tid+it*256; int kk=id>>5, nn=id&31;
    T[kk][nn] = W[(size_t)(k0+kk)*512 + n0+nn];
  }
  __syncthreads();
  #pragma unroll
  for (int it=0; it<4; ++it){
    int id=tid+it*256; int nn=id>>5, kk=id&31;
    WT[(size_t)(n0+nn)*512 + k0+kk] = f2bf(T[kk][nn]);
  }
}

// ---- EFbf = bf16( es @ W_enc + b_enc ), MFMA ----
__global__ __launch_bounds__(256) void k_encm(const float* __restrict__ es,
    const u16* __restrict__ WET, const float* __restrict__ b_enc,
    u16* __restrict__ EFbf){
  __shared__ u16 As[128*40];
  __shared__ u16 Bs[128*40];
  const int tid=threadIdx.x;
  const int m0 = blockIdx.x*128, n0 = blockIdx.y*128;
  const int wid=tid>>6, lane=tid&63;
  const int wm=(wid>>1)*64, wn=(wid&1)*64;
  const int l15=lane&15, l4=lane>>4;
  f32x4 acc[4][4];
  #pragma unroll
  for (int mi=0;mi<4;++mi)
    #pragma unroll
    for (int ni=0;ni<4;++ni) acc[mi][ni] = (f32x4){0.f,0.f,0.f,0.f};
  for (int kt=0; kt<16; ++kt){
    const int k0=kt*32;
    __syncthreads();
    #pragma unroll
    for (int it=0; it<4; ++it){
      int id=tid+it*256; int row=id>>3, q=id&7;
      float4 v = *(const float4*)(es + (size_t)(m0+row)*512 + k0 + q*4);
      u64 pk = (u64)f2bf(v.x) | ((u64)f2bf(v.y)<<16) | ((u64)f2bf(v.z)<<32) | ((u64)f2bf(v.w)<<48);
      *(u64*)&As[row*40 + q*4] = pk;
    }
    #pragma unroll
    for (int it=0; it<2; ++it){
      int id=tid+it*256; int row=id>>2, c4=id&3;
      uint4 v = *(const uint4*)(WET + (size_t)(n0+row)*512 + k0 + c4*8);
      *(uint4*)&Bs[row*40 + c4*8] = v;
    }
    __syncthreads();
    bf16x8 a[4], b[4];
    #pragma unroll
    for (int mi=0;mi<4;++mi) a[mi] = *(const bf16x8*)(&As[(wm+mi*16+l15)*40 + l4*8]);
    #pragma unroll
    for (int ni=0;ni<4;++ni) b[ni] = *(const bf16x8*)(&Bs[(wn+ni*16+l15)*40 + l4*8]);
    #pragma unroll
    for (int mi=0;mi<4;++mi)
      #pragma unroll
      for (int ni=0;ni<4;++ni)
        acc[mi][ni] = __builtin_amdgcn_mfma_f32_16x16x32_bf16(a[mi], b[ni], acc[mi][ni], 0,0,0);
  }
  #pragma unroll
  for (int ni=0;ni<4;++ni){
    const int col = n0+wn+ni*16+l15;
    const float bp = b_enc[col];
    #pragma unroll
    for (int mi=0;mi<4;++mi){
      const int rb = m0+wm+mi*16+l4*4;
      #pragma unroll
      for (int r=0;r<4;++r)
        EFbf[(size_t)(rb+r)*512 + col] = f2bf(acc[mi][ni][r]+bp);
    }
  }
}

// ---- embx + embxp ----
__global__ __launch_bounds__(512) void k_embx(const int* __restrict__ dec_ids,
  const float* __restrict__ emb, const float* __restrict__ W_x,
  const float* __restrict__ Wpgen, float* __restrict__ embx, float* __restrict__ embxp){
  __shared__ float A[16][257];
  __shared__ int ids[16];
  __shared__ float red[8];
  const int tid = threadIdx.x, r0 = blockIdx.x*16;
  if (tid<16){
    int row = r0+tid, tt = row>>5, bb = row&31;
    ids[tid] = dec_ids[bb*Tq + tt];
  }
  __syncthreads();
  for (int idx=tid; idx<16*256; idx+=512){
    int rr = idx>>8, kk = idx&255;
    A[rr][kk] = emb[(size_t)ids[rr]*EMBq + kk];
  }
  __syncthreads();
  float acc[16];
  #pragma unroll
  for (int r=0;r<16;++r) acc[r]=0.f;
  for (int k=0;k<256;++k){
    float w = W_x[(size_t)k*HIDq + tid];
    #pragma unroll
    for (int r=0;r<16;++r) acc[r] += A[r][k]*w;
  }
  float wp4 = Wpgen[1536+tid];
  for (int r=0;r<16;++r){
    embx[(size_t)(r0+r)*HIDq + tid] = acc[r];
    float s = blockSum512(acc[r]*wp4, red);
    if (tid==0) embxp[r0+r] = s;
  }
}

// ---- embz = embx @ Wk + b_lstm ----
__global__ __launch_bounds__(512) void k_embz(const float* __restrict__ embx,
  const float* __restrict__ Wk, const float* __restrict__ b_lstm, float* __restrict__ embz){
  __shared__ float A[16][513];
  const int tid = threadIdx.x;
  const int r0 = blockIdx.x*16;
  const int n  = blockIdx.y*512 + tid;
  for (int idx=tid; idx<16*512; idx+=512){
    int rr=idx>>9, kk=idx&511;
    A[rr][kk] = embx[(size_t)(r0+rr)*HIDq + kk];
  }
  __syncthreads();
  float acc[16];
  #pragma unroll
  for (int r=0;r<16;++r) acc[r]=0.f;
  for (int k=0;k<512;++k){
    float w = Wk[(size_t)k*2048 + n];
    #pragma unroll
    for (int r=0;r<16;++r) acc[r] += A[r][k]*w;
  }
  float bl = b_lstm[n];
  #pragma unroll
  for (int r=0;r<16;++r) embz[(size_t)(r0+r)*2048 + n] = acc[r]+bl;
}

// ---- WXKT[n][j] = sum_i Wk[i][n] * W_x[256+j][i] ----
__global__ __launch_bounds__(512) void k_wxk(const float* __restrict__ Wk,
    const float* __restrict__ W_x, float* __restrict__ WXKT_){
  __shared__ float KT[32][64];
  __shared__ float X2[32][33];
  const int tid = threadIdx.x;
  const int n0 = blockIdx.x * 64;
  const int j0 = blockIdx.y * 32;
  const int jj = tid & 31;
  const int ng = tid >> 5;
  float acc[4] = {0,0,0,0};
  for (int i0=0;i0<512;i0+=32){
    __syncthreads();
    for (int idx=tid; idx<32*64; idx+=512){
      int ii = idx>>6, nn = idx&63;
      KT[ii][nn] = Wk[(size_t)(i0+ii)*2048 + n0+nn];
    }
    for (int idx=tid; idx<32*32; idx+=512){
      int j2 = idx>>5, i2 = idx&31;
      X2[j2][i2] = W_x[(size_t)(256+j0+j2)*HIDq + i0+i2];
    }
    __syncthreads();
    for (int ii=0;ii<32;++ii){
      float xv = X2[jj][ii];
      #pragma unroll
      for (int q=0;q<4;++q) acc[q] += KT[ii][ng*4+q]*xv;
    }
  }
  #pragma unroll
  for (int q=0;q<4;++q) WXKT_[(size_t)(n0+ng*4+q)*512 + j0+jj] = acc[q];
}

// ---- 32x32 transpose ----
__global__ __launch_bounds__(512) void k_trans(const float* __restrict__ in,
    float* __restrict__ out, int K, int N){
  __shared__ float T[32][33];
  const int n0 = blockIdx.x*32, k0 = blockIdx.y*32;
  const int tid = threadIdx.x;
  for (int idx=tid; idx<1024; idx+=512){
    int kk = idx>>5, nn = idx&31;
    T[kk][nn] = in[(size_t)(k0+kk)*N + n0+nn];
  }
  __syncthreads();
  for (int idx=tid; idx<1024; idx+=512){
    int nn = idx>>5, kk = idx&31;
    out[(size_t)(n0+nn)*K + k0+kk] = T[kk][nn];
  }
}

// ---- WGbf[col*4+g][k] = bf16( k<512 ? WXKT[g*512+col][k] : WrT[g*512+col][k-512] ) ----
__global__ __launch_bounds__(512) void k_wgcvt(const float* __restrict__ WXKT_,
    const float* __restrict__ WrT_, u16* __restrict__ WGbf){
  const int np = blockIdx.x;
  const int col = np>>2, g = np&3;
  const int n = g*512 + col;
  const float* s1 = WXKT_ + (size_t)n*512;
  const float* s2 = WrT_  + (size_t)n*512;
  u16* o = WGbf + (size_t)np*1024;
  int k = threadIdx.x;
  o[k]     = f2bf(s1[k]);
  o[512+k] = f2bf(s2[k]);
}

// ---- generic f32 -> bf16 copy ----
__global__ void k_cvt(const float* __restrict__ in, u16* __restrict__ out, int n){
  int i = blockIdx.x*256 + threadIdx.x;
  if (i<n) out[i] = f2bf(in[i]);
}

// ---- Wxp[j] = sum_i W_x[256+j][i]*W_pgen[1536+i] ----
__global__ __launch_bounds__(512) void k_wp(const float* __restrict__ W_x,
  const float* __restrict__ Wpgen, float* __restrict__ Wxp){
  int j = threadIdx.x;
  const float* row = W_x + (size_t)(256+j)*HIDq;
  float s=0.f;
  for (int i=0;i<512;++i) s += row[i]*Wpgen[1536+i];
  Wxp[j] = s;
}

// ==== persistent recurrence: fully group-local (no global barriers) ====
// 256 blocks = 32 batch-groups x 8 s-chunks. Block (b,sc):
//  (1) gate GEMV slice (256 gate-cols) + LSTM for its 64 h-cols -> mbar
//  (2) finalize attn/cov of t-1; stage h,c; df-slice -> mbar
//  (4) e-pass on its 64 s-rows; (5) chunk stats; (6) ctx partial -> mbar
//  (7) ctx+pgen finalize for its 64 j-cols -> mbar
__global__ __launch_bounds__(512,1) void k_rec4(
  const u16* __restrict__ EFbf, const float* __restrict__ mask,
  const float* __restrict__ init_h, const float* __restrict__ init_c,
  const u16* __restrict__ WGbf, const float* __restrict__ embz,
  const u16* __restrict__ WAbf, const float* __restrict__ vvec,
  const float* __restrict__ wcov, const float* __restrict__ bcov,
  const float* __restrict__ Wpgen, const float* __restrict__ Wxp,
  float* __restrict__ Hbuf, float* __restrict__ Cbuf, float* __restrict__ Ctx,
  float* __restrict__ dfg, float* __restrict__ mZ, float* __restrict__ cp,
  float* __restrict__ hc_ws, float* __restrict__ attn_ws, float* __restrict__ pgen_raw,
  unsigned* __restrict__ msl)
{
  __shared__ float xA[1024];
  __shared__ float zl[256];
  __shared__ float cbuf[64];
  __shared__ float covb[64], eprev[64], mzl[16];
  __shared__ float hb[512], cb[512], dfl[512];
  __shared__ float dfpart[8][64];
  __shared__ float el[64], wl[64];

  const int tid = threadIdx.x, bid = blockIdx.x;
  const int lane = tid&63, wv = tid>>6;
  const int bB = bid>>3, sc = bid&7, s0 = sc*64;
  const int j0 = lane*8;
  unsigned* gs = msl + bB*16;

  float vvr[8], wcr[8], bcr[8];
  *(float4*)&vvr[0] = *(const float4*)&vvec[j0]; *(float4*)&vvr[4] = *(const float4*)&vvec[j0+4];
  *(float4*)&wcr[0] = *(const float4*)&wcov[j0]; *(float4*)&wcr[4] = *(const float4*)&wcov[j0+4];
  *(float4*)&bcr[0] = *(const float4*)&bcov[j0]; *(float4*)&bcr[4] = *(const float4*)&bcov[j0+4];

  if (tid<64) cbuf[tid] = init_c[bB*512 + s0 + tid];

  const u16* wrow = WGbf + (size_t)(sc*256 + (tid>>1))*1024 + (size_t)(tid&1)*512;
  const int xbase = (tid&1)*512;

  unsigned mt = 0;

  for (int t=0; t<Tq; ++t){
    // ---- (0) stage x = [ctx_{t-1} ; h_{t-1}] ----
    {
      float xv0, xv1;
      if (t==0){ xv0 = 0.f; xv1 = init_h[bB*512+tid]; }
      else {
        xv0 = ld1(Ctx + bB*512 + tid);
        xv1 = ld1(Hbuf + ((t+1)&1)*16384 + bB*512 + tid);
      }
      xA[tid] = xv0; xA[512+tid] = xv1;
    }
    __syncthreads();
    // ---- (1) gate GEMV slice + LSTM ----
    {
      float acc = 0.f;
      const float* xs = &xA[xbase];
      for (int k=0;k<512;k+=8){
        bf16x8 w8 = *(const bf16x8*)(wrow + k);
        const u16* ph = (const u16*)&w8;
        #pragma unroll
        for (int q=0;q<8;++q) acc += xs[k+q]*bf2f(ph[q]);
      }
      acc += __shfl_xor(acc, 1);
      if ((tid&1)==0) zl[tid>>1] = acc;
    }
    __syncthreads();
    if (tid<64){
      const int colg = s0 + tid;
      const float* ez = embz + ((size_t)t*Bq + bB)*2048 + colg;
      float zi = zl[tid*4+0] + __builtin_nontemporal_load(ez);
      float zf = zl[tid*4+1] + __builtin_nontemporal_load(ez+512);
      float zg = zl[tid*4+2] + __builtin_nontemporal_load(ez+1024);
      float zo = zl[tid*4+3] + __builtin_nontemporal_load(ez+1536);
      float co = cbuf[tid];
      float cn = sigmoidf_(zf)*co + sigmoidf_(zi)*tanhf_(zg);
      float hn = sigmoidf_(zo)*tanhf_(cn);
      cbuf[tid] = cn;
      st1(Cbuf + bB*512 + colg, cn);
      st1(Hbuf + (t&1)*16384 + bB*512 + colg, hn);
      __builtin_nontemporal_store(hn, hc_ws + ((size_t)t*Bq+bB)*1024 + colg);
    }
    ++mt; mbar(gs, sc, mt);
    // ---- (2) finalize attn/cov of t-1 ----
    if (t > 0){
      if (tid<16) mzl[tid] = ld1(mZ + (bB*8+(tid>>1))*2 + (tid&1));
      __syncthreads();
      float M = mzl[0];
      #pragma unroll
      for (int l=1;l<8;++l) M = fmaxf(M, mzl[l*2]);
      float D = 0.f;
      #pragma unroll
      for (int l=0;l<8;++l) D += __expf(mzl[l*2]-M)*mzl[l*2+1];
      if (tid<64){
        float a = mask[bB*512+s0+tid]*__expf(eprev[tid]-M)/D;
        __builtin_nontemporal_store(a, attn_ws + ((size_t)(t-1)*Bq+bB)*Sq + s0+tid);
        covb[tid] = (t==1) ? a : covb[tid]+a;
      }
      __syncthreads();
    }
    // ---- (3) stage h_t, c_t; df-slice ----
    if (tid<256){
      float2 f = ld2(Hbuf + (t&1)*16384 + bB*512 + tid*2);
      hb[tid*2]=f.x; hb[tid*2+1]=f.y;
    } else {
      int q = tid-256;
      float2 f = ld2(Cbuf + bB*512 + q*2);
      cb[q*2]=f.x; cb[q*2+1]=f.y;
    }
    __syncthreads();
    {
      const float* xs = (wv<4) ? &hb[wv*128] : &cb[(wv-4)*128];
      const u16* wa = WAbf + (size_t)(wv*128)*512 + s0 + lane;
      float acc = 0.f;
      #pragma unroll 4
      for (int k=0;k<128;++k) acc += xs[k]*bf2f(wa[(size_t)k*512]);
      dfpart[wv][lane] = acc;
    }
    __syncthreads();
    if (tid<64){
      float d = 0.f;
      #pragma unroll
      for (int w=0;w<8;++w) d += dfpart[w][tid];
      st1(dfg + bB*512 + s0 + tid, d);
    }
    ++mt; mbar(gs, sc, mt);
    // ---- (4) full df; e-pass over 64 s-rows ----
    if (tid<256){
      float2 f = ld2(dfg + bB*512 + tid*2);
      dfl[tid*2]=f.x; dfl[tid*2+1]=f.y;
    }
    __syncthreads();
    {
      float dd[8];
      *(float4*)&dd[0] = *(const float4*)&dfl[j0];
      *(float4*)&dd[4] = *(const float4*)&dfl[j0+4];
      const u16* efb = EFbf + ((size_t)(bB*512 + s0))*512;
      for (int r=0;r<8;++r){
        int sl = wv*8 + r;
        uint4 pack = *(const uint4*)(efb + (size_t)sl*512 + j0);
        const u16* ph = (const u16*)&pack;
        float a8 = 0.f;
        if (t>0){
          float cvs = covb[sl];
          #pragma unroll
          for (int q=0;q<8;++q) a8 += vvr[q]*tanhf_(bf2f(ph[q])+dd[q]+cvs*wcr[q]+bcr[q]);
        } else {
          #pragma unroll
          for (int q=0;q<8;++q) a8 += vvr[q]*tanhf_(bf2f(ph[q])+dd[q]);
        }
        #pragma unroll
        for (int off=32; off>0; off>>=1) a8 += __shfl_down(a8, off);
        if (lane==0) el[sl] = a8;
      }
    }
    __syncthreads();
    // ---- (5) chunk softmax stats ----
    if (tid<64){
      float e = el[tid];
      float m = e;
      #pragma unroll
      for (int off=32; off>0; off>>=1) m = fmaxf(m, __shfl_xor(m, off));
      float w_ = mask[bB*512+s0+tid]*__expf(e-m);
      float Z = w_;
      #pragma unroll
      for (int off=32; off>0; off>>=1) Z += __shfl_xor(Z, off);
      wl[tid] = w_;
      eprev[tid] = e;
      if (tid==0) st2(mZ + (bB*8+sc)*2, m, Z);
    }
    __syncthreads();
    // ---- (6) ctx partial ----
    {
      float acc = 0.f;
      const u16* efc = EFbf + ((size_t)(bB*512+s0))*512 + tid;
      #pragma unroll 4
      for (int s=0;s<64;++s) acc += wl[s]*bf2f(efc[(size_t)s*512]);
      st1(cp + ((size_t)(bB*8+sc))*512 + tid, acc);
    }
    ++mt; mbar(gs, sc, mt);
    // ---- (7) finalize ctx + pgen (own 64-col slice) ----
    if (tid<16) mzl[tid] = ld1(mZ + (bB*8+(tid>>1))*2 + (tid&1));
    __syncthreads();
    {
      float M = mzl[0];
      #pragma unroll
      for (int l=1;l<8;++l) M = fmaxf(M, mzl[l*2]);
      float D = 0.f;
      #pragma unroll
      for (int l=0;l<8;++l) D += __expf(mzl[l*2]-M)*mzl[l*2+1];
      if (tid<64){
        int j = s0 + tid;
        float cold = ld1(Ctx + bB*512 + j);
        float cx = 0.f;
        #pragma unroll
        for (int l=0;l<8;++l) cx += __expf(mzl[l*2]-M)*ld1(cp + ((size_t)(bB*8+l))*512 + j);
        cx /= D;
        st1(Ctx + bB*512 + j, cx);
        __builtin_nontemporal_store(cx, hc_ws + ((size_t)t*Bq+bB)*1024 + 512 + j);
        float part = cx*Wpgen[j] + hb[j]*Wpgen[512+j]
                   + cb[j]*Wpgen[1024+j] + cold*Wxp[j];
        #pragma unroll
        for (int off=32; off>0; off>>=1) part += __shfl_down(part, off);
        if (tid==0)
          __hip_atomic_fetch_add(pgen_raw + t*Bq + bB, part, __ATOMIC_RELAXED, __HIP_MEMORY_SCOPE_AGENT);
      }
    }
    ++mt; mbar(gs, sc, mt);
  }
  // epilogue: attn for t = Tq-1
  {
    if (tid<16) mzl[tid] = ld1(mZ + (bB*8+(tid>>1))*2 + (tid&1));
    __syncthreads();
    float M = mzl[0];
    #pragma unroll
    for (int l=1;l<8;++l) M = fmaxf(M, mzl[l*2]);
    float D = 0.f;
    #pragma unroll
    for (int l=0;l<8;++l) D += __expf(mzl[l*2]-M)*mzl[l*2+1];
    if (tid<64){
      float a = mask[bB*512+s0+tid]*__expf(eprev[tid]-M)/D;
      __builtin_nontemporal_store(a, attn_ws + ((size_t)(Tq-1)*Bq+bB)*Sq + s0+tid);
    }
  }
}

// ---- OUTm = [h,ctx] @ W_out -> bf16 ----
__global__ __launch_bounds__(512) void k_mid(const float* __restrict__ hc,
    const float* __restrict__ W_out, u16* __restrict__ outm_bf){
  __shared__ float A[16][256];
  const int tid=threadIdx.x;
  const int r0=blockIdx.x*16;
  float acc[16];
  #pragma unroll
  for (int r=0;r<16;++r) acc[r]=0.f;
  for (int kc=0;kc<4;++kc){
    __syncthreads();
    for (int i=tid;i<16*256;i+=512){
      int rr=i>>8, kk=i&255;
      A[rr][kk]=hc[(size_t)(r0+rr)*1024 + kc*256+kk];
    }
    __syncthreads();
    for (int k=0;k<256;++k){
      float w=W_out[(size_t)(kc*256+k)*HIDq + tid];
      #pragma unroll
      for (int r=0;r<16;++r) acc[r]+=A[r][k]*w;
    }
  }
  #pragma unroll
  for (int r=0;r<16;++r) outm_bf[(size_t)(r0+r)*HIDq+tid]=f2bf(acc[r]);
}

// ---- W_proj f32 [512][50000] -> WT bf16 [HALF_N][512] ----
__global__ __launch_bounds__(256) void k_wcvt(const float* __restrict__ Wp,
    u16* __restrict__ WT, int n_base){
  __shared__ float T[32][33];
  const int n0 = blockIdx.x*32, k0 = blockIdx.y*32;
  const int tid = threadIdx.x;
  #pragma unroll
  for (int it=0; it<4; ++it){
    int id = tid + it*256;
    int kk = id>>5, nn = id&31;
    int gn = n_base + n0 + nn;
    T[kk][nn] = (gn < VOCABq) ? Wp[(size_t)(k0+kk)*VOCABq + gn] : 0.f;
  }
  __syncthreads();
  #pragma unroll
  for (int it=0; it<4; ++it){
    int id = tid + it*256;
    int nn = id>>5, kk = id&31;
    WT[(size_t)(n0+nn)*512 + k0+kk] = f2bf(T[kk][nn]);
  }
}

// ---- logits = Abf @ WT^T + b_proj -> d_out rows ----
__global__ __launch_bounds__(256) void k_projm(const u16* __restrict__ Abf,
    const u16* __restrict__ WT, const float* __restrict__ b_proj,
    float* __restrict__ out, int n_base){
  __shared__ u16 As[128*40];
  __shared__ u16 Bs[128*40];
  const int tid = threadIdx.x;
  const int m0 = blockIdx.x * 128;
  const int n0 = blockIdx.y * 128;
  const int wid = tid>>6, lane = tid&63;
  const int wm = (wid>>1)*64, wn = (wid&1)*64;
  const int l15 = lane&15, l4 = lane>>4;
  f32x4 acc[4][4];
  #pragma unroll
  for (int mi=0;mi<4;++mi)
    #pragma unroll
    for (int ni=0;ni<4;++ni) acc[mi][ni] = (f32x4){0.f,0.f,0.f,0.f};

  for (int kt=0; kt<16; ++kt){
    const int k0 = kt*32;
    __syncthreads();
    #pragma unroll
    for (int it=0; it<2; ++it){
      int id = tid + it*256;
      int row = id>>2, c4 = id&3;
      uint4 va = *(const uint4*)(Abf + (size_t)(m0+row)*512 + k0 + c4*8);
      *(uint4*)(&As[row*40 + c4*8]) = va;
      uint4 vb = *(const uint4*)(WT + (size_t)(n0+row)*512 + k0 + c4*8);
      *(uint4*)(&Bs[row*40 + c4*8]) = vb;
    }
    __syncthreads();
    bf16x8 a[4], b[4];
    #pragma unroll
    for (int mi=0;mi<4;++mi)
      a[mi] = *(const bf16x8*)(&As[(wm + mi*16 + l15)*40 + l4*8]);
    #pragma unroll
    for (int ni=0;ni<4;++ni)
      b[ni] = *(const bf16x8*)(&Bs[(wn + ni*16 + l15)*40 + l4*8]);
    #pragma unroll
    for (int mi=0;mi<4;++mi)
      #pragma unroll
      for (int ni=0;ni<4;++ni)
        acc[mi][ni] = __builtin_amdgcn_mfma_f32_16x16x32_bf16(a[mi], b[ni], acc[mi][ni], 0,0,0);
  }

  #pragma unroll
  for (int ni=0;ni<4;++ni){
    const int col = n_base + n0 + wn + ni*16 + l15;
    if (col < VOCABq){
      const float bp = b_proj[col];
      #pragma unroll
      for (int mi=0;mi<4;++mi){
        const int rbase = m0 + wm + mi*16 + l4*4;
        #pragma unroll
        for (int r=0;r<4;++r)
          out[(size_t)(rbase+r)*VEXTq + col] = acc[mi][ni][r] + bp;
      }
    }
  }
}

// ---- per-row softmax * p_gen, zero OOV, scatter-add (1-pg)*attn ----
__global__ __launch_bounds__(256) void k_sm(float* __restrict__ out,
    const float* __restrict__ pgen_raw, const float* __restrict__ embxp,
    const float* __restrict__ attn_ws, const int* __restrict__ enc_ids){
  __shared__ float redm[4], reds[4];
  const int row=blockIdx.x, tid=threadIdx.x;
  const int b = row & (Bq-1);
  float* orow = out + (size_t)row*VEXTq;
  float m=-1e30f, s=0.f;
  for (int i=tid;i<VOCABq;i+=256){
    float l=orow[i];
    float nm=fmaxf(m,l);
    s = s*__expf(m-nm) + __expf(l-nm);
    m = nm;
  }
  #pragma unroll
  for (int off=32; off>0; off>>=1){
    float om=__shfl_down(m,off), os=__shfl_down(s,off);
    float nm=fmaxf(m,om);
    s = s*__expf(m-nm)+os*__expf(om-nm);
    m = nm;
  }
  int lane=tid&63, wid=tid>>6;
  if (lane==0){ redm[wid]=m; reds[wid]=s; }
  __syncthreads();
  float M=redm[0];
  #pragma unroll
  for (int w=1;w<4;++w) M=fmaxf(M,redm[w]);
  float Ssum=0.f;
  #pragma unroll
  for (int w=0;w<4;++w) Ssum += reds[w]*__expf(redm[w]-M);
  const float pg = sigmoidf_(pgen_raw[row] + embxp[row]);
  const float scale = pg/Ssum;
  for (int i=tid;i<VOCABq;i+=256) orow[i]=scale*__expf(orow[i]-M);
  for (int i=VOCABq+tid;i<VEXTq;i+=256) orow[i]=0.f;
  __syncthreads();
  const float w1 = 1.f-pg;
  const float* arow = attn_ws + (size_t)row*Sq;
  const int* ids = enc_ids + b*Sq;
  for (int si=tid; si<Sq; si+=256)
    atomicAdd(&orow[ids[si]], w1*arow[si]);
}

extern "C" void kernel_launch(void* const* d_in, const int* in_sizes, int n_in,
                              void* d_out, int out_size, void* d_ws, size_t ws_size,
                              hipStream_t stream) {
  (void)in_sizes; (void)n_in; (void)out_size; (void)ws_size;
  const int*   dec_ids    = (const int*)  d_in[0];
  const int*   enc_ids    = (const int*)  d_in[1];
  const float* enc_states = (const float*)d_in[2];
  const float* mask       = (const float*)d_in[3];
  const float* init_h     = (const float*)d_in[4];
  const float* init_c     = (const float*)d_in[5];
  const float* embeddings = (const float*)d_in[6];
  const float* W_enc      = (const float*)d_in[7];
  const float* b_enc      = (const float*)d_in[8];
  const float* W_attn     = (const float*)d_in[9];
  const float* vvec       = (const float*)d_in[10];
  const float* w_cov      = (const float*)d_in[11];
  const float* b_cov      = (const float*)d_in[12];
  const float* W_x        = (const float*)d_in[13];
  const float* W_out      = (const float*)d_in[14];
  const float* Wk         = (const float*)d_in[15];
  const float* Wr         = (const float*)d_in[16];
  const float* b_lstm     = (const float*)d_in[17];
  const float* W_pgen     = (const float*)d_in[18];
  const float* W_proj     = (const float*)d_in[19];
  const float* b_proj     = (const float*)d_in[20];
  float* out = (float*)d_out;
  float* ws  = (float*)d_ws;

  u16*   EFbf    = (u16*)ws;                          // 8,388,608 u16
  float* attn_ws = ws + 4194304;
  float* hc_ws   = attn_ws + 524288;
  u16*   outm_bf = (u16*)(hc_ws + 1048576);           // 524,288 u16
  float* embx    = hc_ws + 1048576 + 262144;
  float* embxp   = embx + 524288;
  float* embz    = embxp + 1024;
  float* WXKT_   = embz + 2097152;
  float* WrT_    = WXKT_ + 1048576;
  float* Wxp     = WrT_ + 1048576;
  float* Hbuf    = Wxp + 512;                         // 2 x 16384
  float* Cbuf    = Hbuf + 32768;
  float* CtxP    = Cbuf + 16384;
  float* dfg     = CtxP + 16384;
  float* mZ      = dfg + 16384;
  float* cp      = mZ + 512;
  u16*   WGbf    = (u16*)(cp + 131072);               // 2,097,152 u16
  u16*   WAbf    = (u16*)(((float*)WGbf) + 1048576);  // 524,288 u16
  u16*   WET     = (u16*)(((float*)WAbf) + 262144);   // 262,144 u16
  unsigned* msl  = (unsigned*)(((float*)WET) + 131072); // 512 u32 slots
  float* pgen_raw= (float*)(msl + 512);               // 1024
  u16*   WT      = (u16*)(pgen_raw + 1024);           // 12,845,056 u16

  // zero barrier slots + pgen accumulators
  hipMemsetAsync(msl, 0, (512 + 1024)*sizeof(unsigned), stream);

  // ---- precompute ----
  {
    dim3 g(16,16);
    k_wet<<<g, 256, 0, stream>>>(W_enc, WET);
  }
  {
    dim3 g(128,4);
    k_encm<<<g, 256, 0, stream>>>(enc_states, WET, b_enc, EFbf);
  }
  k_embx<<<64, 512, 0, stream>>>(dec_ids, embeddings, W_x, W_pgen, embx, embxp);
  {
    dim3 g(64,4);
    k_embz<<<g, 512, 0, stream>>>(embx, Wk, b_lstm, embz);
  }
  {
    dim3 g(32,16);
    k_wxk<<<g, 512, 0, stream>>>(Wk, W_x, WXKT_);
  }
  {
    dim3 g(64,16);   // Wr [512][2048] -> WrT [2048][512]
    k_trans<<<g, 512, 0, stream>>>(Wr, WrT_, 512, 2048);
  }
  k_wgcvt<<<2048, 512, 0, stream>>>(WXKT_, WrT_, WGbf);
  k_cvt<<<(524288+255)/256, 256, 0, stream>>>(W_attn, WAbf, 524288);
  k_wp<<<1, 512, 0, stream>>>(W_x, W_pgen, Wxp);

  // ---- recurrence: persistent kernel, group-local barriers only ----
  {
    void* args[] = { (void*)&EFbf, (void*)&mask, (void*)&init_h, (void*)&init_c,
                     (void*)&WGbf, (void*)&embz, (void*)&WAbf, (void*)&vvec,
                     (void*)&w_cov, (void*)&b_cov, (void*)&W_pgen, (void*)&Wxp,
                     (void*)&Hbuf, (void*)&Cbuf, (void*)&CtxP,
                     (void*)&dfg, (void*)&mZ, (void*)&cp,
                     (void*)&hc_ws, (void*)&attn_ws, (void*)&pgen_raw,
                     (void*)&msl };
    hipLaunchCooperativeKernel((void*)k_rec4, dim3(256), dim3(512), args, 0, stream);
  }

  // ---- output projection + softmax + scatter ----
  k_mid<<<(Tq*Bq)/16, 512, 0, stream>>>(hc_ws, W_out, outm_bf);
  for (int half=0; half<2; ++half){
    const int n_base = half*HALF_N;
    dim3 gc(HALF_N/32, 16);
    k_wcvt<<<gc, 256, 0, stream>>>(W_proj, WT, n_base);
    dim3 gp(8, HALF_N/128);
    k_projm<<<gp, 256, 0, stream>>>(outm_bf, WT, b_proj, out, n_base);
  }
  k_sm<<<Tq*Bq, 256, 0, stream>>>(out, pgen_raw, embxp, attn_ws, enc_ids);
}

// Round 7
// 2676.408 us; speedup vs baseline: 2.6569x; 1.0121x over previous
//
#include <hip/hip_runtime.h>
#include <math.h>

#define Bq 32
#define Sq 512
#define Tq 32
#define EMBq 256
#define HIDq 512
#define VOCABq 50000
#define OOVq 100
#define VEXTq (VOCABq + OOVq)
#define HALF_N 25088

typedef unsigned short u16;
typedef unsigned long long u64;
typedef __attribute__((ext_vector_type(8))) short bf16x8;
typedef __attribute__((ext_vector_type(4))) float f32x4;

__device__ __forceinline__ float sigmoidf_(float x){ return 1.0f/(1.0f+__expf(-x)); }
__device__ __forceinline__ float tanhf_(float x){ return 1.0f - 2.0f/(__expf(2.0f*x)+1.0f); }

__device__ __forceinline__ u16 f2bf(float x){
  union{float f; unsigned u;} v; v.f=x;
  unsigned r = v.u + 0x7FFFu + ((v.u>>16)&1u);
  return (u16)(r>>16);
}
__device__ __forceinline__ float bf2f(u16 h){
  union{unsigned u; float f;} v; v.u = ((unsigned)h)<<16; return v.f;
}

// ---- agent-scope (L2-bypass, device-coherent) accessors ----
__device__ __forceinline__ float ld1(const float* p){
  return __hip_atomic_load((float*)p, __ATOMIC_RELAXED, __HIP_MEMORY_SCOPE_AGENT);
}
__device__ __forceinline__ void st1(float* p, float v){
  __hip_atomic_store(p, v, __ATOMIC_RELAXED, __HIP_MEMORY_SCOPE_AGENT);
}
__device__ __forceinline__ float2 ld2(const float* p){
  u64 v = __hip_atomic_load((u64*)p, __ATOMIC_RELAXED, __HIP_MEMORY_SCOPE_AGENT);
  union{u64 u; float2 f;} c; c.u=v; return c.f;
}

// ---- group-local barrier: 8 blocks, distributed slots ----
__device__ __forceinline__ void mbar(unsigned* gs, int sc, unsigned tag){
  asm volatile("s_waitcnt vmcnt(0)" ::: "memory");
  __syncthreads();
  if (threadIdx.x==0)
    __hip_atomic_store(gs+sc, tag, __ATOMIC_RELAXED, __HIP_MEMORY_SCOPE_AGENT);
  if (threadIdx.x<64){
    for(;;){
      unsigned v = (threadIdx.x<8)
        ? __hip_atomic_load(gs+threadIdx.x, __ATOMIC_RELAXED, __HIP_MEMORY_SCOPE_AGENT)
        : tag;
      if (__all(v>=tag)) break;
      __builtin_amdgcn_s_sleep(1);
    }
  }
  __syncthreads();
}

__device__ __forceinline__ float blockSum512(float v, float* red){
  #pragma unroll
  for (int off=32; off>0; off>>=1) v += __shfl_down(v, off);
  int lane = threadIdx.x & 63, wid = threadIdx.x >> 6;
  __syncthreads();
  if (lane==0) red[wid]=v;
  __syncthreads();
  float t=0.f;
  #pragma unroll
  for (int w=0;w<8;++w) t+=red[w];
  return t;
}

// ---- W_enc [512k][512n] -> WET bf16 [n][k] ----
__global__ __launch_bounds__(256) void k_wet(const float* __restrict__ W, u16* __restrict__ WT){
  __shared__ float T[32][33];
  const int n0 = blockIdx.x*32, k0 = blockIdx.y*32;
  const int tid=threadIdx.x;
  #pragma unroll
  for (int it=0; it<4; ++it){
    int id = tid+it*256; int kk=id>>5, nn=id&31;
    T[kk][nn] = W[(size_t)(k0+kk)*512 + n0+nn];
  }
  __syncthreads();
  #pragma unroll
  for (int it=0; it<4; ++it){
    int id=tid+it*256; int nn=id>>5, kk=id&31;
    WT[(size_t)(n0+nn)*512 + k0+kk] = f2bf(T[kk][nn]);
  }
}

// ---- EFbf = bf16( es @ W_enc + b_enc ), MFMA ----
__global__ __launch_bounds__(256) void k_encm(const float* __restrict__ es,
    const u16* __restrict__ WET, const float* __restrict__ b_enc,
    u16* __restrict__ EFbf){
  __shared__ u16 As[128*40];
  __shared__ u16 Bs[128*40];
  const int tid=threadIdx.x;
  const int m0 = blockIdx.x*128, n0 = blockIdx.y*128;
  const int wid=tid>>6, lane=tid&63;
  const int wm=(wid>>1)*64, wn=(wid&1)*64;
  const int l15=lane&15, l4=lane>>4;
  f32x4 acc[4][4];
  #pragma unroll
  for (int mi=0;mi<4;++mi)
    #pragma unroll
    for (int ni=0;ni<4;++ni) acc[mi][ni] = (f32x4){0.f,0.f,0.f,0.f};
  for (int kt=0; kt<16; ++kt){
    const int k0=kt*32;
    __syncthreads();
    #pragma unroll
    for (int it=0; it<4; ++it){
      int id=tid+it*256; int row=id>>3, q=id&7;
      float4 v = *(const float4*)(es + (size_t)(m0+row)*512 + k0 + q*4);
      u64 pk = (u64)f2bf(v.x) | ((u64)f2bf(v.y)<<16) | ((u64)f2bf(v.z)<<32) | ((u64)f2bf(v.w)<<48);
      *(u64*)&As[row*40 + q*4] = pk;
    }
    #pragma unroll
    for (int it=0; it<2; ++it){
      int id=tid+it*256; int row=id>>2, c4=id&3;
      uint4 v = *(const uint4*)(WET + (size_t)(n0+row)*512 + k0 + c4*8);
      *(uint4*)&Bs[row*40 + c4*8] = v;
    }
    __syncthreads();
    bf16x8 a[4], b[4];
    #pragma unroll
    for (int mi=0;mi<4;++mi) a[mi] = *(const bf16x8*)(&As[(wm+mi*16+l15)*40 + l4*8]);
    #pragma unroll
    for (int ni=0;ni<4;++ni) b[ni] = *(const bf16x8*)(&Bs[(wn+ni*16+l15)*40 + l4*8]);
    #pragma unroll
    for (int mi=0;mi<4;++mi)
      #pragma unroll
      for (int ni=0;ni<4;++ni)
        acc[mi][ni] = __builtin_amdgcn_mfma_f32_16x16x32_bf16(a[mi], b[ni], acc[mi][ni], 0,0,0);
  }
  #pragma unroll
  for (int ni=0;ni<4;++ni){
    const int col = n0+wn+ni*16+l15;
    const float bp = b_enc[col];
    #pragma unroll
    for (int mi=0;mi<4;++mi){
      const int rb = m0+wm+mi*16+l4*4;
      #pragma unroll
      for (int r=0;r<4;++r)
        EFbf[(size_t)(rb+r)*512 + col] = f2bf(acc[mi][ni][r]+bp);
    }
  }
}

// ---- embx + embxp ----
__global__ __launch_bounds__(512) void k_embx(const int* __restrict__ dec_ids,
  const float* __restrict__ emb, const float* __restrict__ W_x,
  const float* __restrict__ Wpgen, float* __restrict__ embx, float* __restrict__ embxp){
  __shared__ float A[16][257];
  __shared__ int ids[16];
  __shared__ float red[8];
  const int tid = threadIdx.x, r0 = blockIdx.x*16;
  if (tid<16){
    int row = r0+tid, tt = row>>5, bb = row&31;
    ids[tid] = dec_ids[bb*Tq + tt];
  }
  __syncthreads();
  for (int idx=tid; idx<16*256; idx+=512){
    int rr = idx>>8, kk = idx&255;
    A[rr][kk] = emb[(size_t)ids[rr]*EMBq + kk];
  }
  __syncthreads();
  float acc[16];
  #pragma unroll
  for (int r=0;r<16;++r) acc[r]=0.f;
  for (int k=0;k<256;++k){
    float w = W_x[(size_t)k*HIDq + tid];
    #pragma unroll
    for (int r=0;r<16;++r) acc[r] += A[r][k]*w;
  }
  float wp4 = Wpgen[1536+tid];
  for (int r=0;r<16;++r){
    embx[(size_t)(r0+r)*HIDq + tid] = acc[r];
    float s = blockSum512(acc[r]*wp4, red);
    if (tid==0) embxp[r0+r] = s;
  }
}

// ---- embz = embx @ Wk + b_lstm ----
__global__ __launch_bounds__(512) void k_embz(const float* __restrict__ embx,
  const float* __restrict__ Wk, const float* __restrict__ b_lstm, float* __restrict__ embz){
  __shared__ float A[16][513];
  const int tid = threadIdx.x;
  const int r0 = blockIdx.x*16;
  const int n  = blockIdx.y*512 + tid;
  for (int idx=tid; idx<16*512; idx+=512){
    int rr=idx>>9, kk=idx&511;
    A[rr][kk] = embx[(size_t)(r0+rr)*HIDq + kk];
  }
  __syncthreads();
  float acc[16];
  #pragma unroll
  for (int r=0;r<16;++r) acc[r]=0.f;
  for (int k=0;k<512;++k){
    float w = Wk[(size_t)k*2048 + n];
    #pragma unroll
    for (int r=0;r<16;++r) acc[r] += A[r][k]*w;
  }
  float bl = b_lstm[n];
  #pragma unroll
  for (int r=0;r<16;++r) embz[(size_t)(r0+r)*2048 + n] = acc[r]+bl;
}

// ---- WXKT[n][j] = sum_i Wk[i][n] * W_x[256+j][i] ----
__global__ __launch_bounds__(512) void k_wxk(const float* __restrict__ Wk,
    const float* __restrict__ W_x, float* __restrict__ WXKT_){
  __shared__ float KT[32][64];
  __shared__ float X2[32][33];
  const int tid = threadIdx.x;
  const int n0 = blockIdx.x * 64;
  const int j0 = blockIdx.y * 32;
  const int jj = tid & 31;
  const int ng = tid >> 5;
  float acc[4] = {0,0,0,0};
  for (int i0=0;i0<512;i0+=32){
    __syncthreads();
    for (int idx=tid; idx<32*64; idx+=512){
      int ii = idx>>6, nn = idx&63;
      KT[ii][nn] = Wk[(size_t)(i0+ii)*2048 + n0+nn];
    }
    for (int idx=tid; idx<32*32; idx+=512){
      int j2 = idx>>5, i2 = idx&31;
      X2[j2][i2] = W_x[(size_t)(256+j0+j2)*HIDq + i0+i2];
    }
    __syncthreads();
    for (int ii=0;ii<32;++ii){
      float xv = X2[jj][ii];
      #pragma unroll
      for (int q=0;q<4;++q) acc[q] += KT[ii][ng*4+q]*xv;
    }
  }
  #pragma unroll
  for (int q=0;q<4;++q) WXKT_[(size_t)(n0+ng*4+q)*512 + j0+jj] = acc[q];
}

// ---- 32x32 transpose ----
__global__ __launch_bounds__(512) void k_trans(const float* __restrict__ in,
    float* __restrict__ out, int K, int N){
  __shared__ float T[32][33];
  const int n0 = blockIdx.x*32, k0 = blockIdx.y*32;
  const int tid = threadIdx.x;
  for (int idx=tid; idx<1024; idx+=512){
    int kk = idx>>5, nn = idx&31;
    T[kk][nn] = in[(size_t)(k0+kk)*N + n0+nn];
  }
  __syncthreads();
  for (int idx=tid; idx<1024; idx+=512){
    int nn = idx>>5, kk = idx&31;
    out[(size_t)(n0+nn)*K + k0+kk] = T[kk][nn];
  }
}

// ---- WGbf[col*4+g][k] ----
__global__ __launch_bounds__(512) void k_wgcvt(const float* __restrict__ WXKT_,
    const float* __restrict__ WrT_, u16* __restrict__ WGbf){
  const int np = blockIdx.x;
  const int col = np>>2, g = np&3;
  const int n = g*512 + col;
  const float* s1 = WXKT_ + (size_t)n*512;
  const float* s2 = WrT_  + (size_t)n*512;
  u16* o = WGbf + (size_t)np*1024;
  int k = threadIdx.x;
  o[k]     = f2bf(s1[k]);
  o[512+k] = f2bf(s2[k]);
}

// ---- generic f32 -> bf16 copy ----
__global__ void k_cvt(const float* __restrict__ in, u16* __restrict__ out, int n){
  int i = blockIdx.x*256 + threadIdx.x;
  if (i<n) out[i] = f2bf(in[i]);
}

// ---- Wxp[j] = sum_i W_x[256+j][i]*W_pgen[1536+i] ----
__global__ __launch_bounds__(512) void k_wp(const float* __restrict__ W_x,
  const float* __restrict__ Wpgen, float* __restrict__ Wxp){
  int j = threadIdx.x;
  const float* row = W_x + (size_t)(256+j)*HIDq;
  float s=0.f;
  for (int i=0;i<512;++i) s += row[i]*Wpgen[1536+i];
  Wxp[j] = s;
}

// ==== persistent recurrence v5 ====
// Roles: sc = bid>>5 (slice, same-XCD under chunked mapping), bB = bid&31 (batch).
// 3 barriers/step. No-max softmax. ctx combined redundantly in next step's staging.
__global__ __launch_bounds__(512,1) void k_rec5(
  const u16* __restrict__ EFbf, const float* __restrict__ mask,
  const float* __restrict__ init_h, const float* __restrict__ init_c,
  const u16* __restrict__ WGbf, const float* __restrict__ embz,
  const u16* __restrict__ WAbf, const float* __restrict__ vvec,
  const float* __restrict__ wcov, const float* __restrict__ bcov,
  const float* __restrict__ Wpgen, const float* __restrict__ Wxp,
  float* __restrict__ Hbuf, float* __restrict__ Cbuf, float* __restrict__ dfg,
  float* __restrict__ cpb, float* __restrict__ Zp,
  float* __restrict__ hc_ws, float* __restrict__ attn_ws, float* __restrict__ pgen_raw,
  unsigned* __restrict__ msl)
{
  __shared__ float xA[1024];
  __shared__ float zl[256];
  __shared__ float cbuf[64], covb[64], wsv[64], coldv[64];
  __shared__ float hb[512], cb[512], dfl[512];
  __shared__ float dfpart[8][64];
  __shared__ float el[64];
  __shared__ float zsh[8];

  const int tid = threadIdx.x, bid = blockIdx.x;
  const int lane = tid&63, wv = tid>>6;
  const int bB = bid & 31, sc = bid >> 5, s0 = sc*64;
  const int j0 = lane*8;
  unsigned* gs = msl + bB*16;

  float vvr[8], wcr[8], bcr[8];
  *(float4*)&vvr[0] = *(const float4*)&vvec[j0]; *(float4*)&vvr[4] = *(const float4*)&vvec[j0+4];
  *(float4*)&wcr[0] = *(const float4*)&wcov[j0]; *(float4*)&wcr[4] = *(const float4*)&wcov[j0+4];
  *(float4*)&bcr[0] = *(const float4*)&bcov[j0]; *(float4*)&bcr[4] = *(const float4*)&bcov[j0+4];

  if (tid<64){ cbuf[tid] = init_c[bB*512 + s0 + tid]; coldv[tid]=0.f; }

  const u16* wrow = WGbf + (size_t)(sc*256 + (tid>>1))*1024 + (size_t)(tid&1)*512;
  const int xbase = (tid&1)*512;

  unsigned mt = 0;

  for (int t=0; t<Tq; ++t){
    // ---- phase 0: combine prev step (ctx, attn, cov, pgen) + stage x ----
    if (t==0){
      xA[tid] = 0.f;
      xA[512+tid] = init_h[bB*512+tid];
      __syncthreads();
    } else {
      const float* cpp = cpb + ((t-1)&1)*131072 + (size_t)bB*8*512;
      if (tid<8) zsh[tid] = ld1(Zp + ((t-1)&1)*256 + bB*8 + tid);
      __syncthreads();
      float Z = ((zsh[0]+zsh[1])+(zsh[2]+zsh[3]))+((zsh[4]+zsh[5])+(zsh[6]+zsh[7]));
      float cx = 0.f;
      #pragma unroll
      for (int l=0;l<8;++l) cx += ld1(cpp + l*512 + tid);
      cx /= Z;
      float hv = ld1(Hbuf + ((t+1)&1)*16384 + bB*512 + tid);
      if (tid>=s0 && tid<s0+64)
        __builtin_nontemporal_store(cx, hc_ws + ((size_t)(t-1)*Bq+bB)*1024 + 512 + tid);
      xA[tid] = cx; xA[512+tid] = hv;
      __syncthreads();
      if (tid<64){
        float a = wsv[tid] / Z;
        __builtin_nontemporal_store(a, attn_ws + ((size_t)(t-1)*Bq+bB)*Sq + s0+tid);
        covb[tid] = (t==1) ? a : covb[tid]+a;
        int j = s0+tid;
        float part = xA[j]*Wpgen[j] + xA[512+j]*Wpgen[512+j]
                   + cbuf[tid]*Wpgen[1024+j] + coldv[tid]*Wxp[j];
        #pragma unroll
        for (int off=32; off>0; off>>=1) part += __shfl_down(part, off);
        if (tid==0)
          __hip_atomic_fetch_add(pgen_raw + (t-1)*Bq + bB, part, __ATOMIC_RELAXED, __HIP_MEMORY_SCOPE_AGENT);
        coldv[tid] = xA[j];
      }
      __syncthreads();
    }
    // ---- phase 1: gate GEMV slice + LSTM ----
    {
      float acc = 0.f;
      const float* xs = &xA[xbase];
      for (int k=0;k<512;k+=8){
        bf16x8 w8 = *(const bf16x8*)(wrow + k);
        const u16* ph = (const u16*)&w8;
        #pragma unroll
        for (int q=0;q<8;++q) acc += xs[k+q]*bf2f(ph[q]);
      }
      acc += __shfl_xor(acc, 1);
      if ((tid&1)==0) zl[tid>>1] = acc;
    }
    __syncthreads();
    if (tid<64){
      const int colg = s0 + tid;
      const float* ez = embz + ((size_t)t*Bq + bB)*2048 + colg;
      float zi = zl[tid*4+0] + __builtin_nontemporal_load(ez);
      float zf = zl[tid*4+1] + __builtin_nontemporal_load(ez+512);
      float zg = zl[tid*4+2] + __builtin_nontemporal_load(ez+1024);
      float zo = zl[tid*4+3] + __builtin_nontemporal_load(ez+1536);
      float co = cbuf[tid];
      float cn = sigmoidf_(zf)*co + sigmoidf_(zi)*tanhf_(zg);
      float hn = sigmoidf_(zo)*tanhf_(cn);
      cbuf[tid] = cn;
      st1(Cbuf + (t&1)*16384 + bB*512 + colg, cn);
      st1(Hbuf + (t&1)*16384 + bB*512 + colg, hn);
      __builtin_nontemporal_store(hn, hc_ws + ((size_t)t*Bq+bB)*1024 + colg);
    }
    ++mt; mbar(gs, sc, mt);
    // ---- phase 3: stage h_t, c_t; df-slice ----
    if (tid<256){
      float2 f = ld2(Hbuf + (t&1)*16384 + bB*512 + tid*2);
      hb[tid*2]=f.x; hb[tid*2+1]=f.y;
    } else {
      int q = tid-256;
      float2 f = ld2(Cbuf + (t&1)*16384 + bB*512 + q*2);
      cb[q*2]=f.x; cb[q*2+1]=f.y;
    }
    __syncthreads();
    {
      const float* xs = (wv<4) ? &hb[wv*128] : &cb[(wv-4)*128];
      const u16* wa = WAbf + (size_t)(wv*128)*512 + s0 + lane;
      float acc = 0.f;
      #pragma unroll 4
      for (int k=0;k<128;++k) acc += xs[k]*bf2f(wa[(size_t)k*512]);
      dfpart[wv][lane] = acc;
    }
    __syncthreads();
    if (tid<64){
      float d = 0.f;
      #pragma unroll
      for (int w=0;w<8;++w) d += dfpart[w][tid];
      st1(dfg + bB*512 + s0 + tid, d);
    }
    ++mt; mbar(gs, sc, mt);
    // ---- phase 4: full df; e-pass over own 64 s-rows ----
    if (tid<256){
      float2 f = ld2(dfg + bB*512 + tid*2);
      dfl[tid*2]=f.x; dfl[tid*2+1]=f.y;
    }
    __syncthreads();
    {
      float dd[8];
      *(float4*)&dd[0] = *(const float4*)&dfl[j0];
      *(float4*)&dd[4] = *(const float4*)&dfl[j0+4];
      const u16* efb = EFbf + ((size_t)(bB*512 + s0))*512;
      for (int r=0;r<8;++r){
        int sl = wv*8 + r;
        uint4 pack = *(const uint4*)(efb + (size_t)sl*512 + j0);
        const u16* ph = (const u16*)&pack;
        float a8 = 0.f;
        if (t>0){
          float cvs = covb[sl];
          #pragma unroll
          for (int q=0;q<8;++q) a8 += vvr[q]*tanhf_(bf2f(ph[q])+dd[q]+cvs*wcr[q]+bcr[q]);
        } else {
          #pragma unroll
          for (int q=0;q<8;++q) a8 += vvr[q]*tanhf_(bf2f(ph[q])+dd[q]);
        }
        #pragma unroll
        for (int off=32; off>0; off>>=1) a8 += __shfl_down(a8, off);
        if (lane==0) el[sl] = a8;
      }
    }
    __syncthreads();
    // ---- phase 5: no-max chunk weights + Z partial ----
    if (tid<64){
      float w_ = mask[bB*512+s0+tid]*__expf(el[tid]);
      wsv[tid] = w_;
      float Zc = w_;
      #pragma unroll
      for (int off=32; off>0; off>>=1) Zc += __shfl_xor(Zc, off);
      if (tid==0) st1(Zp + (t&1)*256 + bB*8 + sc, Zc);
    }
    __syncthreads();
    // ---- phase 6: ctx partial (unnormalized) ----
    {
      float acc = 0.f;
      const u16* efc = EFbf + ((size_t)(bB*512+s0))*512 + tid;
      #pragma unroll 4
      for (int s=0;s<64;++s) acc += wsv[s]*bf2f(efc[(size_t)s*512]);
      st1(cpb + (t&1)*131072 + ((size_t)(bB*8+sc))*512 + tid, acc);
    }
    ++mt; mbar(gs, sc, mt);
  }
  // ---- epilogue: finalize step Tq-1 (ctx, attn, pgen) ----
  {
    const int t = Tq;
    const float* cpp = cpb + ((t-1)&1)*131072 + (size_t)bB*8*512;
    if (tid<8) zsh[tid] = ld1(Zp + ((t-1)&1)*256 + bB*8 + tid);
    __syncthreads();
    float Z = ((zsh[0]+zsh[1])+(zsh[2]+zsh[3]))+((zsh[4]+zsh[5])+(zsh[6]+zsh[7]));
    float cx = 0.f;
    #pragma unroll
    for (int l=0;l<8;++l) cx += ld1(cpp + l*512 + tid);
    cx /= Z;
    float hv = ld1(Hbuf + ((t+1)&1)*16384 + bB*512 + tid);
    if (tid>=s0 && tid<s0+64)
      __builtin_nontemporal_store(cx, hc_ws + ((size_t)(t-1)*Bq+bB)*1024 + 512 + tid);
    xA[tid] = cx; xA[512+tid] = hv;
    __syncthreads();
    if (tid<64){
      float a = wsv[tid] / Z;
      __builtin_nontemporal_store(a, attn_ws + ((size_t)(t-1)*Bq+bB)*Sq + s0+tid);
      int j = s0+tid;
      float part = xA[j]*Wpgen[j] + xA[512+j]*Wpgen[512+j]
                 + cbuf[tid]*Wpgen[1024+j] + coldv[tid]*Wxp[j];
      #pragma unroll
      for (int off=32; off>0; off>>=1) part += __shfl_down(part, off);
      if (tid==0)
        __hip_atomic_fetch_add(pgen_raw + (t-1)*Bq + bB, part, __ATOMIC_RELAXED, __HIP_MEMORY_SCOPE_AGENT);
    }
  }
}

// ---- OUTm = [h,ctx] @ W_out -> bf16 ----
__global__ __launch_bounds__(512) void k_mid(const float* __restrict__ hc,
    const float* __restrict__ W_out, u16* __restrict__ outm_bf){
  __shared__ float A[16][256];
  const int tid=threadIdx.x;
  const int r0=blockIdx.x*16;
  float acc[16];
  #pragma unroll
  for (int r=0;r<16;++r) acc[r]=0.f;
  for (int kc=0;kc<4;++kc){
    __syncthreads();
    for (int i=tid;i<16*256;i+=512){
      int rr=i>>8, kk=i&255;
      A[rr][kk]=hc[(size_t)(r0+rr)*1024 + kc*256+kk];
    }
    __syncthreads();
    for (int k=0;k<256;++k){
      float w=W_out[(size_t)(kc*256+k)*HIDq + tid];
      #pragma unroll
      for (int r=0;r<16;++r) acc[r]+=A[r][k]*w;
    }
  }
  #pragma unroll
  for (int r=0;r<16;++r) outm_bf[(size_t)(r0+r)*HIDq+tid]=f2bf(acc[r]);
}

// ---- W_proj f32 [512][50000] -> WT bf16 [HALF_N][512] ----
__global__ __launch_bounds__(256) void k_wcvt(const float* __restrict__ Wp,
    u16* __restrict__ WT, int n_base){
  __shared__ float T[32][33];
  const int n0 = blockIdx.x*32, k0 = blockIdx.y*32;
  const int tid = threadIdx.x;
  #pragma unroll
  for (int it=0; it<4; ++it){
    int id = tid + it*256;
    int kk = id>>5, nn = id&31;
    int gn = n_base + n0 + nn;
    T[kk][nn] = (gn < VOCABq) ? Wp[(size_t)(k0+kk)*VOCABq + gn] : 0.f;
  }
  __syncthreads();
  #pragma unroll
  for (int it=0; it<4; ++it){
    int id = tid + it*256;
    int nn = id>>5, kk = id&31;
    WT[(size_t)(n0+nn)*512 + k0+kk] = f2bf(T[kk][nn]);
  }
}

// ---- logits = Abf @ WT^T + b_proj -> d_out rows ----
__global__ __launch_bounds__(256) void k_projm(const u16* __restrict__ Abf,
    const u16* __restrict__ WT, const float* __restrict__ b_proj,
    float* __restrict__ out, int n_base){
  __shared__ u16 As[128*40];
  __shared__ u16 Bs[128*40];
  const int tid = threadIdx.x;
  const int m0 = blockIdx.x * 128;
  const int n0 = blockIdx.y * 128;
  const int wid = tid>>6, lane = tid&63;
  const int wm = (wid>>1)*64, wn = (wid&1)*64;
  const int l15 = lane&15, l4 = lane>>4;
  f32x4 acc[4][4];
  #pragma unroll
  for (int mi=0;mi<4;++mi)
    #pragma unroll
    for (int ni=0;ni<4;++ni) acc[mi][ni] = (f32x4){0.f,0.f,0.f,0.f};

  for (int kt=0; kt<16; ++kt){
    const int k0 = kt*32;
    __syncthreads();
    #pragma unroll
    for (int it=0; it<2; ++it){
      int id = tid + it*256;
      int row = id>>2, c4 = id&3;
      uint4 va = *(const uint4*)(Abf + (size_t)(m0+row)*512 + k0 + c4*8);
      *(uint4*)(&As[row*40 + c4*8]) = va;
      uint4 vb = *(const uint4*)(WT + (size_t)(n0+row)*512 + k0 + c4*8);
      *(uint4*)(&Bs[row*40 + c4*8]) = vb;
    }
    __syncthreads();
    bf16x8 a[4], b[4];
    #pragma unroll
    for (int mi=0;mi<4;++mi)
      a[mi] = *(const bf16x8*)(&As[(wm + mi*16 + l15)*40 + l4*8]);
    #pragma unroll
    for (int ni=0;ni<4;++ni)
      b[ni] = *(const bf16x8*)(&Bs[(wn + ni*16 + l15)*40 + l4*8]);
    #pragma unroll
    for (int mi=0;mi<4;++mi)
      #pragma unroll
      for (int ni=0;ni<4;++ni)
        acc[mi][ni] = __builtin_amdgcn_mfma_f32_16x16x32_bf16(a[mi], b[ni], acc[mi][ni], 0,0,0);
  }

  #pragma unroll
  for (int ni=0;ni<4;++ni){
    const int col = n_base + n0 + wn + ni*16 + l15;
    if (col < VOCABq){
      const float bp = b_proj[col];
      #pragma unroll
      for (int mi=0;mi<4;++mi){
        const int rbase = m0 + wm + mi*16 + l4*4;
        #pragma unroll
        for (int r=0;r<4;++r)
          out[(size_t)(rbase+r)*VEXTq + col] = acc[mi][ni][r] + bp;
      }
    }
  }
}

// ---- per-row softmax * p_gen, zero OOV, scatter-add (1-pg)*attn ----
__global__ __launch_bounds__(256) void k_sm(float* __restrict__ out,
    const float* __restrict__ pgen_raw, const float* __restrict__ embxp,
    const float* __restrict__ attn_ws, const int* __restrict__ enc_ids){
  __shared__ float redm[4], reds[4];
  const int row=blockIdx.x, tid=threadIdx.x;
  const int b = row & (Bq-1);
  float* orow = out + (size_t)row*VEXTq;
  float m=-1e30f, s=0.f;
  for (int i=tid;i<VOCABq;i+=256){
    float l=orow[i];
    float nm=fmaxf(m,l);
    s = s*__expf(m-nm) + __expf(l-nm);
    m = nm;
  }
  #pragma unroll
  for (int off=32; off>0; off>>=1){
    float om=__shfl_down(m,off), os=__shfl_down(s,off);
    float nm=fmaxf(m,om);
    s = s*__expf(m-nm)+os*__expf(om-nm);
    m = nm;
  }
  int lane=tid&63, wid=tid>>6;
  if (lane==0){ redm[wid]=m; reds[wid]=s; }
  __syncthreads();
  float M=redm[0];
  #pragma unroll
  for (int w=1;w<4;++w) M=fmaxf(M,redm[w]);
  float Ssum=0.f;
  #pragma unroll
  for (int w=0;w<4;++w) Ssum += reds[w]*__expf(redm[w]-M);
  const float pg = sigmoidf_(pgen_raw[row] + embxp[row]);
  const float scale = pg/Ssum;
  for (int i=tid;i<VOCABq;i+=256) orow[i]=scale*__expf(orow[i]-M);
  for (int i=VOCABq+tid;i<VEXTq;i+=256) orow[i]=0.f;
  __syncthreads();
  const float w1 = 1.f-pg;
  const float* arow = attn_ws + (size_t)row*Sq;
  const int* ids = enc_ids + b*Sq;
  for (int si=tid; si<Sq; si+=256)
    atomicAdd(&orow[ids[si]], w1*arow[si]);
}

extern "C" void kernel_launch(void* const* d_in, const int* in_sizes, int n_in,
                              void* d_out, int out_size, void* d_ws, size_t ws_size,
                              hipStream_t stream) {
  (void)in_sizes; (void)n_in; (void)out_size; (void)ws_size;
  const int*   dec_ids    = (const int*)  d_in[0];
  const int*   enc_ids    = (const int*)  d_in[1];
  const float* enc_states = (const float*)d_in[2];
  const float* mask       = (const float*)d_in[3];
  const float* init_h     = (const float*)d_in[4];
  const float* init_c     = (const float*)d_in[5];
  const float* embeddings = (const float*)d_in[6];
  const float* W_enc      = (const float*)d_in[7];
  const float* b_enc      = (const float*)d_in[8];
  const float* W_attn     = (const float*)d_in[9];
  const float* vvec       = (const float*)d_in[10];
  const float* w_cov      = (const float*)d_in[11];
  const float* b_cov      = (const float*)d_in[12];
  const float* W_x        = (const float*)d_in[13];
  const float* W_out      = (const float*)d_in[14];
  const float* Wk         = (const float*)d_in[15];
  const float* Wr         = (const float*)d_in[16];
  const float* b_lstm     = (const float*)d_in[17];
  const float* W_pgen     = (const float*)d_in[18];
  const float* W_proj     = (const float*)d_in[19];
  const float* b_proj     = (const float*)d_in[20];
  float* out = (float*)d_out;
  float* ws  = (float*)d_ws;

  u16*   EFbf    = (u16*)ws;                          // 8,388,608 u16
  float* attn_ws = ws + 4194304;
  float* hc_ws   = attn_ws + 524288;
  u16*   outm_bf = (u16*)(hc_ws + 1048576);           // 524,288 u16
  float* embx    = hc_ws + 1048576 + 262144;
  float* embxp   = embx + 524288;
  float* embz    = embxp + 1024;
  float* WXKT_   = embz + 2097152;
  float* WrT_    = WXKT_ + 1048576;
  float* Wxp     = WrT_ + 1048576;
  float* Hbuf    = Wxp + 512;                         // 2 x 16384
  float* Cbuf    = Hbuf + 32768;                      // 2 x 16384
  float* dfg     = Cbuf + 32768;                      // 16384
  float* cpb     = dfg + 16384;                       // 2 x 131072
  float* Zp      = cpb + 262144;                      // 2 x 256
  u16*   WGbf    = (u16*)(Zp + 512);                  // 2,097,152 u16
  u16*   WAbf    = (u16*)(((float*)WGbf) + 1048576);  // 524,288 u16
  u16*   WET     = (u16*)(((float*)WAbf) + 262144);   // 262,144 u16
  unsigned* msl  = (unsigned*)(((float*)WET) + 131072); // 512 u32
  float* pgen_raw= (float*)(msl + 512);               // 1024
  u16*   WT      = (u16*)(pgen_raw + 1024);           // 12,845,056 u16

  // zero barrier slots + pgen accumulators
  hipMemsetAsync(msl, 0, (512 + 1024)*sizeof(unsigned), stream);

  // ---- precompute ----
  {
    dim3 g(16,16);
    k_wet<<<g, 256, 0, stream>>>(W_enc, WET);
  }
  {
    dim3 g(128,4);
    k_encm<<<g, 256, 0, stream>>>(enc_states, WET, b_enc, EFbf);
  }
  k_embx<<<64, 512, 0, stream>>>(dec_ids, embeddings, W_x, W_pgen, embx, embxp);
  {
    dim3 g(64,4);
    k_embz<<<g, 512, 0, stream>>>(embx, Wk, b_lstm, embz);
  }
  {
    dim3 g(32,16);
    k_wxk<<<g, 512, 0, stream>>>(Wk, W_x, WXKT_);
  }
  {
    dim3 g(64,16);   // Wr [512][2048] -> WrT [2048][512]
    k_trans<<<g, 512, 0, stream>>>(Wr, WrT_, 512, 2048);
  }
  k_wgcvt<<<2048, 512, 0, stream>>>(WXKT_, WrT_, WGbf);
  k_cvt<<<(524288+255)/256, 256, 0, stream>>>(W_attn, WAbf, 524288);
  k_wp<<<1, 512, 0, stream>>>(W_x, W_pgen, Wxp);

  // ---- recurrence ----
  {
    void* args[] = { (void*)&EFbf, (void*)&mask, (void*)&init_h, (void*)&init_c,
                     (void*)&WGbf, (void*)&embz, (void*)&WAbf, (void*)&vvec,
                     (void*)&w_cov, (void*)&b_cov, (void*)&W_pgen, (void*)&Wxp,
                     (void*)&Hbuf, (void*)&Cbuf, (void*)&dfg, (void*)&cpb, (void*)&Zp,
                     (void*)&hc_ws, (void*)&attn_ws, (void*)&pgen_raw,
                     (void*)&msl };
    hipLaunchCooperativeKernel((void*)k_rec5, dim3(256), dim3(512), args, 0, stream);
  }

  // ---- output projection + softmax + scatter ----
  k_mid<<<(Tq*Bq)/16, 512, 0, stream>>>(hc_ws, W_out, outm_bf);
  for (int half=0; half<2; ++half){
    const int n_base = half*HALF_N;
    dim3 gc(HALF_N/32, 16);
    k_wcvt<<<gc, 256, 0, stream>>>(W_proj, WT, n_base);
    dim3 gp(8, HALF_N/128);
    k_projm<<<gp, 256, 0, stream>>>(outm_bf, WT, b_proj, out, n_base);
  }
  k_sm<<<Tq*Bq, 256, 0, stream>>>(out, pgen_raw, embxp, attn_ws, enc_ids);
}